// Round 4
// baseline (601.723 us; speedup 1.0000x reference)
//
#include <hip/hip_runtime.h>

// Problem constants
#define BB 16
#define SS 1024
#define DD 768

typedef _Float16 f16x4 __attribute__((ext_vector_type(4)));
typedef _Float16 f16x8 __attribute__((ext_vector_type(8)));
typedef float f32x4 __attribute__((ext_vector_type(4)));

__device__ __forceinline__ void gload_lds16(const void* g, void* l) {
  __builtin_amdgcn_global_load_lds(
      (const __attribute__((address_space(1))) unsigned int*)g,
      (__attribute__((address_space(3))) unsigned int*)l, 16, 0, 0);
}

// ---------------------------------------------------------------------------
// 256x256 deep-pipelined NT GEMM (T3+T4): fp16 in, fp32 MFMA accumulate.
// C[z][m][n] = sum_k A[z][m][k] * Bt[z][n][k] (+ bias[z][n])
// 512 threads = 8 waves (2 M x 4 N), per-wave 128x64 output, BK=32.
// LDS: ring of 4 K-tile slots x (A 16KB + B 16KB) = 128 KiB.
// K-tile LDS layout is k-chunk-major [kb(4)][row(256)][8 f16] so fragment
// ds_read_b128 is bank-conflict-free; staged via per-lane permuted global
// source addresses (gload_lds dest stays linear).
// Pipeline: iter t computes slot t&3, prefetches tile t+3 (slot (t-1)&3,
// whose reads retired before this iter's barrier). Wait = counted vmcnt(8)
// (tiles t+1,t+2 stay in flight), then s_barrier -> all waves' staging of
// tile t is visible. No vmcnt(0) drain in the main loop.
// OUTM: 0 = fp32 row-major; 3 = f16, z<2 row-major / z==2 transposed;
//       4 = f16, z<2 transposed / z==2 row-major. Transposed = per-1024-row
//       batch: C[z][(b*N+c)*1024 + s], b=row>>10, s=row&1023.
// ---------------------------------------------------------------------------
template<int OUTM, int BIAS>
__global__ __launch_bounds__(512) void gemm256(
    const _Float16* __restrict__ A, long long aB,
    const _Float16* __restrict__ Bt, long long bB,
    const float* __restrict__ bias, int biasB,
    void* __restrict__ Cv, long long cB,
    int M, int N, int K)
{
  __shared__ __attribute__((aligned(16))) _Float16 lds[65536];  // 128 KiB
  const int t = threadIdx.x;
  const int z = blockIdx.z;
  const int m0 = blockIdx.x * 256, n0 = blockIdx.y * 256;
  const _Float16* Ab = A + (size_t)z * aB;
  const _Float16* Bb = Bt + (size_t)z * bB;

  // Staging: thread t stages LDS chunk (kb0, rr) at issue0, (kb0+2, rr) at issue1
  const int rr = t & 255, kb0 = t >> 8;
  const char* gA = (const char*)(Ab + (size_t)(m0 + rr) * K) + kb0 * 16;
  const char* gB = (const char*)(Bb + (size_t)(n0 + rr) * K) + kb0 * 16;
  char* const ldsb = (char*)lds;
  const int d0 = t * 16;  // linear dest byte offset within a 8KB issue-half

  const int NTk = K >> 5;  // K-tiles of 32

  // Prologue: stage tiles 0,1,2 (12 loads/thread in flight)
  #pragma unroll
  for (int p = 0; p < 3; ++p) {
    char* la = ldsb + p * 32768;
    const char* ga = gA + p * 64;
    const char* gb = gB + p * 64;
    gload_lds16(ga,      la + d0);
    gload_lds16(ga + 32, la + 8192 + d0);
    gload_lds16(gb,      la + 16384 + d0);
    gload_lds16(gb + 32, la + 24576 + d0);
  }

  const int l = t & 63, w = t >> 6;
  const int wr = (w >> 2) * 128, wc = (w & 3) * 64;
  const int lrow = l & 15, kq = l >> 4;

  f32x4 acc[8][4] = {};

  for (int tt = 0; tt < NTk; ++tt) {
    const int rem = NTk - 1 - tt;
    if (rem >= 2)      asm volatile("s_waitcnt vmcnt(8)" ::: "memory");
    else if (rem == 1) asm volatile("s_waitcnt vmcnt(4)" ::: "memory");
    else               asm volatile("s_waitcnt vmcnt(0)" ::: "memory");
    __builtin_amdgcn_s_barrier();
    asm volatile("" ::: "memory");  // keep LDS ops on the right side of the barrier

    // Prefetch tile tt+3 into slot (tt+3)&3 (== slot (tt-1)&3, reads retired)
    if (tt + 3 < NTk) {
      char* la = ldsb + ((tt + 3) & 3) * 32768;
      const char* ga = gA + (size_t)(tt + 3) * 64;
      const char* gb = gB + (size_t)(tt + 3) * 64;
      gload_lds16(ga,      la + d0);
      gload_lds16(ga + 32, la + 8192 + d0);
      gload_lds16(gb,      la + 16384 + d0);
      gload_lds16(gb + 32, la + 24576 + d0);
    }

    const _Float16* la = (const _Float16*)(ldsb + (tt & 3) * 32768);
    const _Float16* lb = la + 8192;
    f16x8 bfr[4], af[8];
    #pragma unroll
    for (int n = 0; n < 4; ++n)
      bfr[n] = *(const f16x8*)&lb[kq * 2048 + (wc + n * 16 + lrow) * 8];
    #pragma unroll
    for (int m = 0; m < 8; ++m)
      af[m] = *(const f16x8*)&la[kq * 2048 + (wr + m * 16 + lrow) * 8];

    __builtin_amdgcn_s_setprio(1);
    #pragma unroll
    for (int m = 0; m < 8; ++m)
      #pragma unroll
      for (int n = 0; n < 4; ++n)
        acc[m][n] = __builtin_amdgcn_mfma_f32_16x16x32_f16(af[m], bfr[n], acc[m][n], 0, 0, 0);
    __builtin_amdgcn_s_setprio(0);
  }

  // Epilogue. C/D layout: col = lane&15, row = 4*(lane>>4) + j
  const int crow = (l >> 4) * 4, ccol = l & 15;
  #pragma unroll
  for (int m = 0; m < 8; ++m) {
    const int rq = m0 + wr + m * 16 + crow;
    #pragma unroll
    for (int n = 0; n < 4; ++n) {
      const int c = n0 + wc + n * 16 + ccol;
      const float bv = BIAS ? bias[(size_t)z * biasB + c] : 0.0f;
      if (OUTM == 0) {
        float* C = (float*)Cv + (size_t)z * cB;
        #pragma unroll
        for (int j = 0; j < 4; j++)
          C[(size_t)(rq + j) * N + c] = acc[m][n][j] + bv;
      } else {
        _Float16* C = (_Float16*)Cv + (size_t)z * cB;
        const bool tr = (OUTM == 3) ? (z == 2) : (z < 2);
        if (tr) {
          const int bq = rq >> 10, s = rq & 1023;
          f16x4 o;
          #pragma unroll
          for (int j = 0; j < 4; j++) o[j] = (_Float16)(acc[m][n][j] + bv);
          *(f16x4*)&C[((size_t)(bq * N + c) << 10) + s] = o;
        } else {
          #pragma unroll
          for (int j = 0; j < 4; j++)
            C[(size_t)(rq + j) * N + c] = (_Float16)(acc[m][n][j] + bv);
        }
      }
    }
  }
}

// fp32 -> fp16 elementwise cast
__global__ __launch_bounds__(256) void cast_f2h(const float* __restrict__ in,
                                                _Float16* __restrict__ outp, long long n4)
{
  for (long long i = (long long)blockIdx.x * 256 + threadIdx.x; i < n4;
       i += (long long)gridDim.x * 256) {
    float4 v = ((const float4*)in)[i];
    f16x4 r;
    r[0] = (_Float16)v.x; r[1] = (_Float16)v.y; r[2] = (_Float16)v.z; r[3] = (_Float16)v.w;
    ((f16x4*)outp)[i] = r;
  }
}

// fp32 [R][C] -> fp16 [C][R] (weights transpose+cast)
__global__ __launch_bounds__(256) void transpose_f2h(const float* __restrict__ in,
                                                     _Float16* __restrict__ outp, int R, int C)
{
  __shared__ float tile[32][33];
  const int r0 = blockIdx.y * 32, c0 = blockIdx.x * 32;
  const int tx = threadIdx.x & 31, ty = threadIdx.x >> 5;  // 32 x 8
  #pragma unroll
  for (int i = 0; i < 4; i++)
    tile[ty + i * 8][tx] = in[(size_t)(r0 + ty + i * 8) * C + c0 + tx];
  __syncthreads();
  #pragma unroll
  for (int i = 0; i < 4; i++)
    outp[(size_t)(c0 + ty + i * 8) * R + r0 + tx] = (_Float16)tile[tx][ty + i * 8];
}

// fp16 [R][C] -> [C][R], batched over blockIdx.z
__global__ __launch_bounds__(256) void transpose_b2h(const _Float16* __restrict__ in, long long inB,
                                                     _Float16* __restrict__ outp, long long outB,
                                                     int R, int C)
{
  __shared__ _Float16 tile[32][33];
  const _Float16* ib = in + (size_t)blockIdx.z * inB;
  _Float16* ob = outp + (size_t)blockIdx.z * outB;
  const int r0 = blockIdx.y * 32, c0 = blockIdx.x * 32;
  const int tx = threadIdx.x & 31, ty = threadIdx.x >> 5;
  #pragma unroll
  for (int i = 0; i < 4; i++)
    tile[ty + i * 8][tx] = ib[(size_t)(r0 + ty + i * 8) * C + c0 + tx];
  __syncthreads();
  #pragma unroll
  for (int i = 0; i < 4; i++)
    ob[(size_t)(c0 + ty + i * 8) * R + r0 + tx] = tile[tx][ty + i * 8];
}

__global__ void pack_bias(const float* __restrict__ a, const float* __restrict__ b,
                          const float* __restrict__ c, float* __restrict__ o)
{
  int t = blockIdx.x * 256 + threadIdx.x;
  if (t < 768) o[t] = a[t];
  else if (t < 1536) o[t] = b[t - 768];
  else if (t < 2304) o[t] = c[t - 1536];
}

// Row softmax: fp32 in, fp16 out. L = VPT*256.
template<int VPT>
__global__ __launch_bounds__(256) void softmax_f2h(const float* __restrict__ X,
                                                   _Float16* __restrict__ Y,
                                                   int L, float scale)
{
  const size_t base = (size_t)blockIdx.x * L;
  const int t = threadIdx.x;
  float v[VPT];
  float m = -3.4e38f;
  #pragma unroll
  for (int j = 0; j < VPT; j++) { v[j] = X[base + t + j * 256]; m = fmaxf(m, v[j]); }
  __shared__ float red[256];
  red[t] = m; __syncthreads();
  #pragma unroll
  for (int off = 128; off > 0; off >>= 1) {
    if (t < off) red[t] = fmaxf(red[t], red[t + off]);
    __syncthreads();
  }
  m = red[0]; __syncthreads();
  float s = 0.0f;
  #pragma unroll
  for (int j = 0; j < VPT; j++) { v[j] = __expf((v[j] - m) * scale); s += v[j]; }
  red[t] = s; __syncthreads();
  #pragma unroll
  for (int off = 128; off > 0; off >>= 1) {
    if (t < off) red[t] += red[t + off];
    __syncthreads();
  }
  const float inv = 1.0f / red[0];
  #pragma unroll
  for (int j = 0; j < VPT; j++) Y[base + t + j * 256] = (_Float16)(v[j] * inv);
}

// LayerNorm over (S,D) jointly per batch
__global__ __launch_bounds__(256) void ln_partial(const float* __restrict__ src,
                                                  float* __restrict__ part)
{
  const int b = blockIdx.y, ch = blockIdx.x;   // 64 chunks per batch
  const float4* p = (const float4*)(src + (size_t)b * SS * DD) + (size_t)ch * 3072;
  const int t = threadIdx.x;
  float s = 0.0f, q = 0.0f;
  #pragma unroll
  for (int i = 0; i < 12; i++) {
    float4 v = p[t + i * 256];
    s += v.x + v.y + v.z + v.w;
    q += v.x * v.x + v.y * v.y + v.z * v.z + v.w * v.w;
  }
  __shared__ float rs[256], rq[256];
  rs[t] = s; rq[t] = q; __syncthreads();
  #pragma unroll
  for (int off = 128; off > 0; off >>= 1) {
    if (t < off) { rs[t] += rs[t + off]; rq[t] += rq[t + off]; }
    __syncthreads();
  }
  if (t == 0) { part[(b * 64 + ch) * 2] = rs[0]; part[(b * 64 + ch) * 2 + 1] = rq[0]; }
}

__global__ void ln_final(const float* __restrict__ part, float* __restrict__ stats)
{
  const int b = blockIdx.x, t = threadIdx.x;  // 64 threads = 1 wave
  float s = part[(b * 64 + t) * 2];
  float q = part[(b * 64 + t) * 2 + 1];
  #pragma unroll
  for (int off = 32; off > 0; off >>= 1) { s += __shfl_down(s, off); q += __shfl_down(q, off); }
  if (t == 0) {
    const float invN = 1.0f / (float)(SS * DD);
    float mu = s * invN;
    float var = q * invN - mu * mu;
    stats[b * 2] = mu;
    stats[b * 2 + 1] = rsqrtf(var + 1e-8f);
  }
}

__global__ __launch_bounds__(256) void ln_apply_h(const float* __restrict__ src,
                                                  const float* __restrict__ g,
                                                  const float* __restrict__ bta,
                                                  const float* __restrict__ stats,
                                                  _Float16* __restrict__ dst)
{
  const long long n4 = (long long)BB * SS * DD / 4;
  const int SD4 = SS * DD / 4;
  for (long long i = (long long)blockIdx.x * 256 + threadIdx.x; i < n4;
       i += (long long)gridDim.x * 256) {
    const int b = (int)(i / SD4);
    const int sd4 = (int)(i - (long long)b * SD4);
    const float mu = stats[b * 2], rs = stats[b * 2 + 1];
    float4 v = ((const float4*)src)[i];
    float4 gg = ((const float4*)g)[sd4];
    float4 bb = ((const float4*)bta)[sd4];
    f16x4 r;
    r[0] = (_Float16)((v.x - mu) * rs * gg.x + bb.x);
    r[1] = (_Float16)((v.y - mu) * rs * gg.y + bb.y);
    r[2] = (_Float16)((v.z - mu) * rs * gg.z + bb.z);
    r[3] = (_Float16)((v.w - mu) * rs * gg.w + bb.w);
    ((f16x4*)dst)[i] = r;
  }
}

// gate[b,s] = dot(out_N[b,s,:], W_sgsa) + b_sgsa ; one wave per row
__global__ __launch_bounds__(256) void gate_k(const float* __restrict__ outN,
                                              const float* __restrict__ wsg,
                                              const float* __restrict__ bsg,
                                              float* __restrict__ gate)
{
  const int row = blockIdx.x * 4 + (threadIdx.x >> 6);
  const int l = threadIdx.x & 63;
  const float* src = outN + (size_t)row * DD;
  float s = 0.0f;
  #pragma unroll
  for (int i = 0; i < 12; i++) s += src[l + i * 64] * wsg[l + i * 64];
  #pragma unroll
  for (int off = 32; off > 0; off >>= 1) s += __shfl_down(s, off);
  if (l == 0) gate[row] = s + bsg[0];
}

// Pool stage A: grid (32 chunks, 16 batches); each block: 32 rows x 768 cols
__global__ __launch_bounds__(256) void pool_partial(const float* __restrict__ tokens,
                                                    const float* __restrict__ outN,
                                                    const float* __restrict__ gate,
                                                    float* __restrict__ part)
{
  const int b = blockIdx.y, ch = blockIdx.x, t = threadIdx.x;
  float st0 = 0, st1 = 0, st2 = 0, so0 = 0, so1 = 0, so2 = 0;
  float xt0 = -3.4e38f, xt1 = -3.4e38f, xt2 = -3.4e38f;
  float xo0 = -3.4e38f, xo1 = -3.4e38f, xo2 = -3.4e38f;
  const size_t rowbase = ((size_t)b * SS + ch * 32) * DD;
  for (int i = 0; i < 32; i++) {
    const float* tr = tokens + rowbase + (size_t)i * DD;
    const float* orw = outN + rowbase + (size_t)i * DD;
    const float g = gate[b * SS + ch * 32 + i];
    float t0 = tr[t], t1 = tr[t + 256], t2 = tr[t + 512];
    float o0 = orw[t] * g, o1 = orw[t + 256] * g, o2 = orw[t + 512] * g;
    st0 += t0; st1 += t1; st2 += t2;
    so0 += o0; so1 += o1; so2 += o2;
    xt0 = fmaxf(xt0, t0); xt1 = fmaxf(xt1, t1); xt2 = fmaxf(xt2, t2);
    xo0 = fmaxf(xo0, o0); xo1 = fmaxf(xo1, o1); xo2 = fmaxf(xo2, o2);
  }
  float* pb = part + (size_t)(b * 32 + ch) * 3072;
  pb[t] = st0;          pb[t + 256] = st1;          pb[t + 512] = st2;
  pb[768 + t] = so0;    pb[768 + t + 256] = so1;    pb[768 + t + 512] = so2;
  pb[1536 + t] = xt0;   pb[1536 + t + 256] = xt1;   pb[1536 + t + 512] = xt2;
  pb[2304 + t] = xo0;   pb[2304 + t + 256] = xo1;   pb[2304 + t + 512] = xo2;
}

// Pool stage B: combine 32 chunks -> pooled [B][4*768]
__global__ __launch_bounds__(256) void pool_final(const float* __restrict__ part,
                                                  float* __restrict__ pooled)
{
  const int idx = blockIdx.x * 256 + threadIdx.x;  // < B*D
  const int b = idx / DD, d = idx - b * DD;
  float st = 0, so = 0, xt = -3.4e38f, xo = -3.4e38f;
  for (int ch = 0; ch < 32; ch++) {
    const float* pb = part + (size_t)(b * 32 + ch) * 3072;
    st += pb[d]; so += pb[768 + d];
    xt = fmaxf(xt, pb[1536 + d]); xo = fmaxf(xo, pb[2304 + d]);
  }
  const float inv = 1.0f / (float)SS;
  pooled[(size_t)b * 3072 + d]        = st * inv;
  pooled[(size_t)b * 3072 + 768 + d]  = so * inv;
  pooled[(size_t)b * 3072 + 1536 + d] = xt;
  pooled[(size_t)b * 3072 + 2304 + d] = xo;
}

__global__ __launch_bounds__(256) void fc_k(const float* __restrict__ pooled,
                                            const float* __restrict__ Wf,
                                            const float* __restrict__ bf,
                                            float* __restrict__ outp)
{
  const int b = blockIdx.x, t = threadIdx.x;
  float p0 = 0.0f, p1 = 0.0f;
  #pragma unroll
  for (int i = 0; i < 12; i++) {
    const int j = t + i * 256;
    const float pv = pooled[(size_t)b * 3072 + j];
    p0 += pv * Wf[j * 2];
    p1 += pv * Wf[j * 2 + 1];
  }
  __shared__ float r0[256], r1[256];
  r0[t] = p0; r1[t] = p1; __syncthreads();
  #pragma unroll
  for (int off = 128; off > 0; off >>= 1) {
    if (t < off) { r0[t] += r0[t + off]; r1[t] += r1[t + off]; }
    __syncthreads();
  }
  if (t == 0) {
    outp[b * 2 + 0] = r0[0] + bf[0];
    outp[b * 2 + 1] = r1[0] + bf[1];
  }
}

// ---------------------------------------------------------------------------
// Host orchestration. fp16 GEMM I/O, fp32 softmax/LN/pool chain.
// Region map (byte offsets), peak ~202 MB:
//   R0 @ 0         (67.1MB f32): scores -> OUT -> attN_sc -> outN
//   R1 @ 67108864  (25.2MB f16): tokens_h -> out_ln_h -> attNT_h
//   R2 @ 92274688  (25.2MB f16): K_h -> KtN_h      (plane 0 of proj out)
//   R3 @ 117440512 (25.2MB f16): Q_h -> QtN_h      (plane 1)
//   R4 @ 142606336 (25.2MB f16): Vt_h -> VN_h      (plane 2)
//   R5 @ 167772160 (33.6MB f16): att_h -> attN_h
//   Wt @ 201326592 (3.5MB f16):  [3][768*768]
// ---------------------------------------------------------------------------
extern "C" void kernel_launch(void* const* d_in, const int* in_sizes, int n_in,
                              void* d_out, int out_size, void* d_ws, size_t ws_size,
                              hipStream_t stream)
{
  const float* tokens = (const float*)d_in[0];
  const float* Wk  = (const float*)d_in[1];
  const float* bk  = (const float*)d_in[2];
  const float* Wq  = (const float*)d_in[3];
  const float* bq  = (const float*)d_in[4];
  const float* Wv  = (const float*)d_in[5];
  const float* bv  = (const float*)d_in[6];
  const float* lng = (const float*)d_in[7];
  const float* lnb = (const float*)d_in[8];
  const float* Wsg = (const float*)d_in[9];
  const float* bsg = (const float*)d_in[10];
  const float* Wf  = (const float*)d_in[11];
  const float* bfn = (const float*)d_in[12];
  float* outp = (float*)d_out;
  (void)in_sizes; (void)n_in; (void)out_size; (void)ws_size;

  char* ws = (char*)d_ws;
  float*    R0   = (float*)(ws + 0);
  _Float16* R1   = (_Float16*)(ws + 67108864);
  _Float16* R2   = (_Float16*)(ws + 92274688);
  _Float16* R3   = (_Float16*)(ws + 117440512);
  _Float16* R4   = (_Float16*)(ws + 142606336);
  _Float16* R5   = (_Float16*)(ws + 167772160);
  _Float16* Wt   = (_Float16*)(ws + 201326592);   // 3,538,944 B
  float* bias3   = (float*)(ws + 204865536);      // 9,216 B
  float* part    = (float*)(ws + 204874752);      // 8,192 B
  float* stats   = (float*)(ws + 204882944);      // 128 B
  float* gate    = (float*)(ws + 204883072);      // 65,536 B
  float* ppart   = (float*)(ws + 204948608);      // 6,291,456 B
  float* pooled  = (float*)(ws + 211240064);      // 196,608 B (end ~201.7MB)

  const float fact = 0.036084391824351615f;  // 1/sqrt(768)
  const long long SD = (long long)SS * DD;   // 786432
  const long long S2 = (long long)SS * SS;   // 1048576
  const long long D2 = (long long)DD * DD;   // 589824
  const long long PL = (long long)BB * SD;   // 12582912 (one K/Q/V plane)

  // 1. casts / packing
  cast_f2h<<<2048, 256, 0, stream>>>(tokens, R1, PL / 4);
  transpose_f2h<<<dim3(24, 24), 256, 0, stream>>>(Wk, Wt,               768, 768);
  transpose_f2h<<<dim3(24, 24), 256, 0, stream>>>(Wq, Wt + 589824,      768, 768);
  transpose_f2h<<<dim3(24, 24), 256, 0, stream>>>(Wv, Wt + 2 * 589824,  768, 768);
  pack_bias<<<9, 256, 0, stream>>>(bk, bq, bv, bias3);

  // 2. Stage-1 projections, one launch: z0=K (R2), z1=Q (R3), z2=Vt (R4, transposed)
  gemm256<3, 1><<<dim3(64, 3, 3), 512, 0, stream>>>(R1, 0, Wt, 589824, bias3, 768,
                                                    (void*)R2, PL, BB * SS, DD, DD);
  // 3. scores = Q.K^T -> R0 fp32 [B,S,S]
  gemm256<0, 0><<<dim3(4, 4, 16), 512, 0, stream>>>(R3, SD, R2, SD, nullptr, 0,
                                                    (void*)R0, S2, SS, SS, DD);
  // 4. att_h = softmax(scores*fact) -> R5 fp16
  softmax_f2h<4><<<BB * SS, 256, 0, stream>>>(R0, R5, SS, fact);
  // 5. OUT = att @ V -> R0 fp32 [B,S,D]
  gemm256<0, 0><<<dim3(4, 3, 16), 512, 0, stream>>>(R5, S2, R4, SD, nullptr, 0,
                                                    (void*)R0, SD, SS, DD, SS);
  // 6. LayerNorm over (S,D) per batch: stats from fp32, out_ln_h -> R1 fp16
  ln_partial<<<dim3(64, 16), 256, 0, stream>>>(R0, part);
  ln_final<<<16, 64, 0, stream>>>(part, stats);
  ln_apply_h<<<2048, 256, 0, stream>>>(R0, lng, lnb, stats, R1);

  // 7. Stage-2 projections: z0=KtN (R2, tr), z1=QtN (R3, tr), z2=VN (R4, row-major)
  gemm256<4, 1><<<dim3(64, 3, 3), 512, 0, stream>>>(R1, 0, Wt, 589824, bias3, 768,
                                                    (void*)R2, PL, BB * SS, DD, DD);
  // 8. attN_sc[b,d,e] = QtN .NT. KtN -> R0 fp32 [B,D,D]
  gemm256<0, 0><<<dim3(3, 3, 16), 512, 0, stream>>>(R3, SD, R2, SD, nullptr, 0,
                                                    (void*)R0, D2, DD, DD, SS);
  // 9. attN_h = softmax -> R5 fp16
  softmax_f2h<3><<<BB * DD, 256, 0, stream>>>(R0, R5, DD, fact);
  // 10. attNT_h -> R1 (out_ln dead)
  transpose_b2h<<<dim3(24, 24, 16), 256, 0, stream>>>(R5, D2, R1, D2, DD, DD);
  // 11. outN = VN .NT. attNT -> R0 fp32 [B,S,D]
  gemm256<0, 0><<<dim3(4, 3, 16), 512, 0, stream>>>(R4, SD, R1, D2, nullptr, 0,
                                                    (void*)R0, SD, SS, DD, DD);

  // 12. gate, two-stage pooling, FC
  gate_k<<<4096, 256, 0, stream>>>(R0, Wsg, bsg, gate);
  pool_partial<<<dim3(32, BB), 256, 0, stream>>>(tokens, R0, gate, ppart);
  pool_final<<<48, 256, 0, stream>>>(ppart, pooled);
  fc_k<<<16, 256, 0, stream>>>(pooled, Wf, bfn, outp);
}

// Round 6
// 456.963 us; speedup vs baseline: 1.3168x; 1.3168x over previous
//
#include <hip/hip_runtime.h>

// Problem constants
#define BB 16
#define SS 1024
#define DD 768

typedef _Float16 f16x4 __attribute__((ext_vector_type(4)));
typedef _Float16 f16x8 __attribute__((ext_vector_type(8)));
typedef float f32x4 __attribute__((ext_vector_type(4)));

__device__ __forceinline__ void gload_lds16(const void* g, void* l) {
  __builtin_amdgcn_global_load_lds(
      (const __attribute__((address_space(1))) unsigned int*)g,
      (__attribute__((address_space(3))) unsigned int*)l, 16, 0, 0);
}

// ---------------------------------------------------------------------------
// 256x256 NT GEMM, 4-phase/K-tile pipelined (T3+T4+T5). fp16 in, fp32 acc.
// C[z][m][n] = sum_k A[z][m][k] * Bt[z][n][k] (+ bias[z][n])
// 512 threads = 8 waves (2M x 4N), per-wave 128x64 out (8x4 frags), BK=64.
//
// LDS: 2 dbuf sides x {A,B} x 2 k-slabs x 16KB = 128 KiB.
// Slab layout (row-pair interleaved, 128B rows -> conflict-free reads):
//   slab = [128 pairs][8 chunks x 16B]; pair P, lds-chunk q holds
//   global row 2P + ((q^(P&7))&1), k-chunk (q^(P&7))>>1 of the slab.
//   (involution: q_lds = ((chunk<<1)|(row&1)) ^ (P&7) on BOTH sides)
//   Staging: thread t -> p=t>>3, q=t&7, u=q^(p&7): src row 2p+(u&1),
//   16B chunk u>>1 (within the row's 64B slab segment -> coalescing keeps
//   16 full cachelines per wave). Dest stays linear (t*16; +8192 for pairs
//   64-127 = rows 128-255). Reads: per 16-lane phase each 16B slot is hit
//   by exactly 2 lanes -> minimum aliasing, free (m136).
//
// Schedule per tile T (sides: sd = T&1 read, sn = sd^1 written):
//   p0: vmcnt(4); barrier; stage A-s0(T+1); read B-s0 + A-s0(m-half0); 16 MFMA
//   p1:           barrier; stage B-s0(T+1); read A-s0(m-half1);        16 MFMA
//   p2: vmcnt(4/0); barrier; stage A-s1(T+1); read B-s1 + A-s1(m0);    16 MFMA
//   p3:           barrier; stage B-s1(T+1); read A-s1(m1);             16 MFMA
// vmcnt(4): loads retire oldest-first; at p0 the 4 oldest outstanding are
// exactly {A-s0,B-s0}(T); at p2 {A-s1,B-s1}(T). Issue->wait distance = 4
// phases; 4 loads always remain in flight except the final drain.
// WAR safety: stg at p_i of tile T writes side sn, whose tile-T-1 readers
// all consumed their ds_reads (MFMA data-dep) before the p0 barrier of T.
//
// OUTM: 0 = fp32 row-major; 3 = f16, z<2 row-major / z==2 transposed;
//       4 = f16, z<2 transposed / z==2 row-major. Transposed = per-1024-row
//       batch: C[z][(b*N+c)*1024 + s], b=row>>10, s=row&1023.
// ---------------------------------------------------------------------------
template<int OUTM, int BIAS>
__global__ __launch_bounds__(512) void gemm256(
    const _Float16* __restrict__ A, long long aB,
    const _Float16* __restrict__ Bt, long long bB,
    const float* __restrict__ bias, int biasB,
    void* __restrict__ Cv, long long cB,
    int M, int N, int K)
{
  __shared__ __attribute__((aligned(16))) _Float16 lds[65536];  // 128 KiB
  const int t = threadIdx.x;
  const int z = blockIdx.z;
  const int m0 = blockIdx.x * 256, n0 = blockIdx.y * 256;
  const _Float16* Ab = A + (size_t)z * aB;
  const _Float16* Bb = Bt + (size_t)z * bB;

  const int l = t & 63, w = t >> 6;
  const int wr = (w >> 2) * 128, wc = (w & 3) * 64;
  const int lrow = l & 15, kq = l >> 4;
  // read-side swizzle (lane-constant): within-slab byte offset for the
  // fragment at tile-row base+lrow, k-chunk kq:  base*64 + fragoff
  const int qread = ((kq << 1) | (lrow & 1)) ^ (lrow >> 1);
  const int fragoff = (lrow >> 1) * 128 + qread * 16;

  // staging lane constants (inverse of the same involution)
  const int sp = t >> 3, sq = t & 7;
  const int su = sq ^ (sp & 7);
  const size_t ldK = (size_t)K * 2;
  const char* pA0 = (const char*)Ab + (size_t)(m0 + 2 * sp + (su & 1)) * ldK + (su >> 1) * 16;
  const char* pA1 = pA0 + (size_t)128 * ldK;
  const char* pB0 = (const char*)Bb + (size_t)(n0 + 2 * sp + (su & 1)) * ldK + (su >> 1) * 16;
  const char* pB1 = pB0 + (size_t)128 * ldK;
  char* const ldsb = (char*)lds;
  const int dstt = t * 16;

  // stage one 16KB unit (mat: 0=A,1=B; k-slab s) of K-tile T into side sd
  auto stg = [&](int mat, int s, int T, int sd) {
    const char* g0 = (mat ? pB0 : pA0) + (size_t)T * 128 + s * 64;
    const char* g1 = (mat ? pB1 : pA1) + (size_t)T * 128 + s * 64;
    char* d = ldsb + sd * 65536 + mat * 32768 + s * 16384 + dstt;
    gload_lds16(g0, d);
    gload_lds16(g1, d + 8192);
  };

  f32x4 acc[8][4] = {};
  f16x8 af[4], bfr[4];

#define LOAD_B(S) { _Pragma("unroll") for (int n = 0; n < 4; n++) \
    bfr[n] = *(const f16x8*)(Bbase + (S) * 16384 + (wc + n * 16) * 64 + fragoff); }
#define LOAD_A(S, QM) { _Pragma("unroll") for (int mi = 0; mi < 4; mi++) \
    af[mi] = *(const f16x8*)(Abase + (S) * 16384 + (wr + (QM) * 64 + mi * 16) * 64 + fragoff); }
#define MFMA16(QM) { __builtin_amdgcn_s_setprio(1); \
    _Pragma("unroll") for (int mi = 0; mi < 4; mi++) { \
      _Pragma("unroll") for (int n = 0; n < 4; n++) \
        acc[(QM) * 4 + mi][n] = __builtin_amdgcn_mfma_f32_16x16x32_f16( \
            af[mi], bfr[n], acc[(QM) * 4 + mi][n], 0, 0, 0); } \
    __builtin_amdgcn_s_setprio(0); }

  // prologue: tile 0 -> side 0 (issue order = steady-state order)
  stg(0, 0, 0, 0); stg(1, 0, 0, 0); stg(0, 1, 0, 0); stg(1, 1, 0, 0);

  const int NT = K >> 6;
  for (int T = 0; T < NT; ++T) {
    const int sd = T & 1, sn = sd ^ 1;
    const char* Abase = ldsb + sd * 65536;
    const char* Bbase = Abase + 32768;
    const bool pf = (T + 1) < NT;

    // ---- phase 0: slab 0, m-half 0
    asm volatile("s_waitcnt vmcnt(4)" ::: "memory");
    __builtin_amdgcn_s_barrier();
    asm volatile("" ::: "memory");
    if (pf) stg(0, 0, T + 1, sn);
    LOAD_B(0)
    LOAD_A(0, 0)
    MFMA16(0)
    // ---- phase 1: slab 0, m-half 1
    __builtin_amdgcn_s_barrier();
    asm volatile("" ::: "memory");
    if (pf) stg(1, 0, T + 1, sn);
    LOAD_A(0, 1)
    MFMA16(1)
    // ---- phase 2: slab 1, m-half 0
    if (pf) asm volatile("s_waitcnt vmcnt(4)" ::: "memory");
    else    asm volatile("s_waitcnt vmcnt(0)" ::: "memory");
    __builtin_amdgcn_s_barrier();
    asm volatile("" ::: "memory");
    if (pf) stg(0, 1, T + 1, sn);
    LOAD_B(1)
    LOAD_A(1, 0)
    MFMA16(0)
    // ---- phase 3: slab 1, m-half 1
    __builtin_amdgcn_s_barrier();
    asm volatile("" ::: "memory");
    if (pf) stg(1, 1, T + 1, sn);
    LOAD_A(1, 1)
    MFMA16(1)
  }
#undef LOAD_A
#undef LOAD_B
#undef MFMA16

  // Epilogue. C/D layout: col = lane&15, row = 4*(lane>>4)+j.
  // acc[m] covers row wr + (m>>2)*64 + (m&3)*16.
  const int crow = (l >> 4) * 4, ccol = l & 15;
  #pragma unroll
  for (int m = 0; m < 8; ++m) {
    const int rq = m0 + wr + (m >> 2) * 64 + (m & 3) * 16 + crow;
    #pragma unroll
    for (int n = 0; n < 4; ++n) {
      const int c = n0 + wc + n * 16 + ccol;
      const float bv = BIAS ? bias[(size_t)z * biasB + c] : 0.0f;
      if (OUTM == 0) {
        float* C = (float*)Cv + (size_t)z * cB;
        #pragma unroll
        for (int j = 0; j < 4; j++)
          C[(size_t)(rq + j) * N + c] = acc[m][n][j] + bv;
      } else {
        _Float16* C = (_Float16*)Cv + (size_t)z * cB;
        const bool tr = (OUTM == 3) ? (z == 2) : (z < 2);
        if (tr) {
          const int bq = rq >> 10, s = rq & 1023;
          f16x4 o;
          #pragma unroll
          for (int j = 0; j < 4; j++) o[j] = (_Float16)(acc[m][n][j] + bv);
          *(f16x4*)&C[((size_t)(bq * N + c) << 10) + s] = o;
        } else {
          #pragma unroll
          for (int j = 0; j < 4; j++)
            C[(size_t)(rq + j) * N + c] = (_Float16)(acc[m][n][j] + bv);
        }
      }
    }
  }
}

// fp32 -> fp16 elementwise cast
__global__ __launch_bounds__(256) void cast_f2h(const float* __restrict__ in,
                                                _Float16* __restrict__ outp, long long n4)
{
  for (long long i = (long long)blockIdx.x * 256 + threadIdx.x; i < n4;
       i += (long long)gridDim.x * 256) {
    float4 v = ((const float4*)in)[i];
    f16x4 r;
    r[0] = (_Float16)v.x; r[1] = (_Float16)v.y; r[2] = (_Float16)v.z; r[3] = (_Float16)v.w;
    ((f16x4*)outp)[i] = r;
  }
}

// fp32 [R][C] -> fp16 [C][R] (weights transpose+cast)
__global__ __launch_bounds__(256) void transpose_f2h(const float* __restrict__ in,
                                                     _Float16* __restrict__ outp, int R, int C)
{
  __shared__ float tile[32][33];
  const int r0 = blockIdx.y * 32, c0 = blockIdx.x * 32;
  const int tx = threadIdx.x & 31, ty = threadIdx.x >> 5;  // 32 x 8
  #pragma unroll
  for (int i = 0; i < 4; i++)
    tile[ty + i * 8][tx] = in[(size_t)(r0 + ty + i * 8) * C + c0 + tx];
  __syncthreads();
  #pragma unroll
  for (int i = 0; i < 4; i++)
    outp[(size_t)(c0 + ty + i * 8) * R + r0 + tx] = (_Float16)tile[tx][ty + i * 8];
}

// fp16 [R][C] -> [C][R], batched over blockIdx.z
__global__ __launch_bounds__(256) void transpose_b2h(const _Float16* __restrict__ in, long long inB,
                                                     _Float16* __restrict__ outp, long long outB,
                                                     int R, int C)
{
  __shared__ _Float16 tile[32][33];
  const _Float16* ib = in + (size_t)blockIdx.z * inB;
  _Float16* ob = outp + (size_t)blockIdx.z * outB;
  const int r0 = blockIdx.y * 32, c0 = blockIdx.x * 32;
  const int tx = threadIdx.x & 31, ty = threadIdx.x >> 5;
  #pragma unroll
  for (int i = 0; i < 4; i++)
    tile[ty + i * 8][tx] = ib[(size_t)(r0 + ty + i * 8) * C + c0 + tx];
  __syncthreads();
  #pragma unroll
  for (int i = 0; i < 4; i++)
    ob[(size_t)(c0 + ty + i * 8) * R + r0 + tx] = tile[tx][ty + i * 8];
}

__global__ void pack_bias(const float* __restrict__ a, const float* __restrict__ b,
                          const float* __restrict__ c, float* __restrict__ o)
{
  int t = blockIdx.x * 256 + threadIdx.x;
  if (t < 768) o[t] = a[t];
  else if (t < 1536) o[t] = b[t - 768];
  else if (t < 2304) o[t] = c[t - 1536];
}

// Row softmax: fp32 in, fp16 out. L = VPT*256.
template<int VPT>
__global__ __launch_bounds__(256) void softmax_f2h(const float* __restrict__ X,
                                                   _Float16* __restrict__ Y,
                                                   int L, float scale)
{
  const size_t base = (size_t)blockIdx.x * L;
  const int t = threadIdx.x;
  float v[VPT];
  float m = -3.4e38f;
  #pragma unroll
  for (int j = 0; j < VPT; j++) { v[j] = X[base + t + j * 256]; m = fmaxf(m, v[j]); }
  __shared__ float red[256];
  red[t] = m; __syncthreads();
  #pragma unroll
  for (int off = 128; off > 0; off >>= 1) {
    if (t < off) red[t] = fmaxf(red[t], red[t + off]);
    __syncthreads();
  }
  m = red[0]; __syncthreads();
  float s = 0.0f;
  #pragma unroll
  for (int j = 0; j < VPT; j++) { v[j] = __expf((v[j] - m) * scale); s += v[j]; }
  red[t] = s; __syncthreads();
  #pragma unroll
  for (int off = 128; off > 0; off >>= 1) {
    if (t < off) red[t] += red[t + off];
    __syncthreads();
  }
  const float inv = 1.0f / red[0];
  #pragma unroll
  for (int j = 0; j < VPT; j++) Y[base + t + j * 256] = (_Float16)(v[j] * inv);
}

// LayerNorm over (S,D) jointly per batch
__global__ __launch_bounds__(256) void ln_partial(const float* __restrict__ src,
                                                  float* __restrict__ part)
{
  const int b = blockIdx.y, ch = blockIdx.x;   // 64 chunks per batch
  const float4* p = (const float4*)(src + (size_t)b * SS * DD) + (size_t)ch * 3072;
  const int t = threadIdx.x;
  float s = 0.0f, q = 0.0f;
  #pragma unroll
  for (int i = 0; i < 12; i++) {
    float4 v = p[t + i * 256];
    s += v.x + v.y + v.z + v.w;
    q += v.x * v.x + v.y * v.y + v.z * v.z + v.w * v.w;
  }
  __shared__ float rs[256], rq[256];
  rs[t] = s; rq[t] = q; __syncthreads();
  #pragma unroll
  for (int off = 128; off > 0; off >>= 1) {
    if (t < off) { rs[t] += rs[t + off]; rq[t] += rq[t + off]; }
    __syncthreads();
  }
  if (t == 0) { part[(b * 64 + ch) * 2] = rs[0]; part[(b * 64 + ch) * 2 + 1] = rq[0]; }
}

__global__ void ln_final(const float* __restrict__ part, float* __restrict__ stats)
{
  const int b = blockIdx.x, t = threadIdx.x;  // 64 threads = 1 wave
  float s = part[(b * 64 + t) * 2];
  float q = part[(b * 64 + t) * 2 + 1];
  #pragma unroll
  for (int off = 32; off > 0; off >>= 1) { s += __shfl_down(s, off); q += __shfl_down(q, off); }
  if (t == 0) {
    const float invN = 1.0f / (float)(SS * DD);
    float mu = s * invN;
    float var = q * invN - mu * mu;
    stats[b * 2] = mu;
    stats[b * 2 + 1] = rsqrtf(var + 1e-8f);
  }
}

__global__ __launch_bounds__(256) void ln_apply_h(const float* __restrict__ src,
                                                  const float* __restrict__ g,
                                                  const float* __restrict__ bta,
                                                  const float* __restrict__ stats,
                                                  _Float16* __restrict__ dst)
{
  const long long n4 = (long long)BB * SS * DD / 4;
  const int SD4 = SS * DD / 4;
  for (long long i = (long long)blockIdx.x * 256 + threadIdx.x; i < n4;
       i += (long long)gridDim.x * 256) {
    const int b = (int)(i / SD4);
    const int sd4 = (int)(i - (long long)b * SD4);
    const float mu = stats[b * 2], rs = stats[b * 2 + 1];
    float4 v = ((const float4*)src)[i];
    float4 gg = ((const float4*)g)[sd4];
    float4 bb = ((const float4*)bta)[sd4];
    f16x4 r;
    r[0] = (_Float16)((v.x - mu) * rs * gg.x + bb.x);
    r[1] = (_Float16)((v.y - mu) * rs * gg.y + bb.y);
    r[2] = (_Float16)((v.z - mu) * rs * gg.z + bb.z);
    r[3] = (_Float16)((v.w - mu) * rs * gg.w + bb.w);
    ((f16x4*)dst)[i] = r;
  }
}

// gate[b,s] = dot(out_N[b,s,:], W_sgsa) + b_sgsa ; one wave per row
__global__ __launch_bounds__(256) void gate_k(const float* __restrict__ outN,
                                              const float* __restrict__ wsg,
                                              const float* __restrict__ bsg,
                                              float* __restrict__ gate)
{
  const int row = blockIdx.x * 4 + (threadIdx.x >> 6);
  const int l = threadIdx.x & 63;
  const float* src = outN + (size_t)row * DD;
  float s = 0.0f;
  #pragma unroll
  for (int i = 0; i < 12; i++) s += src[l + i * 64] * wsg[l + i * 64];
  #pragma unroll
  for (int off = 32; off > 0; off >>= 1) s += __shfl_down(s, off);
  if (l == 0) gate[row] = s + bsg[0];
}

// Pool stage A: grid (32 chunks, 16 batches); each block: 32 rows x 768 cols
__global__ __launch_bounds__(256) void pool_partial(const float* __restrict__ tokens,
                                                    const float* __restrict__ outN,
                                                    const float* __restrict__ gate,
                                                    float* __restrict__ part)
{
  const int b = blockIdx.y, ch = blockIdx.x, t = threadIdx.x;
  float st0 = 0, st1 = 0, st2 = 0, so0 = 0, so1 = 0, so2 = 0;
  float xt0 = -3.4e38f, xt1 = -3.4e38f, xt2 = -3.4e38f;
  float xo0 = -3.4e38f, xo1 = -3.4e38f, xo2 = -3.4e38f;
  const size_t rowbase = ((size_t)b * SS + ch * 32) * DD;
  for (int i = 0; i < 32; i++) {
    const float* tr = tokens + rowbase + (size_t)i * DD;
    const float* orw = outN + rowbase + (size_t)i * DD;
    const float g = gate[b * SS + ch * 32 + i];
    float t0 = tr[t], t1 = tr[t + 256], t2 = tr[t + 512];
    float o0 = orw[t] * g, o1 = orw[t + 256] * g, o2 = orw[t + 512] * g;
    st0 += t0; st1 += t1; st2 += t2;
    so0 += o0; so1 += o1; so2 += o2;
    xt0 = fmaxf(xt0, t0); xt1 = fmaxf(xt1, t1); xt2 = fmaxf(xt2, t2);
    xo0 = fmaxf(xo0, o0); xo1 = fmaxf(xo1, o1); xo2 = fmaxf(xo2, o2);
  }
  float* pb = part + (size_t)(b * 32 + ch) * 3072;
  pb[t] = st0;          pb[t + 256] = st1;          pb[t + 512] = st2;
  pb[768 + t] = so0;    pb[768 + t + 256] = so1;    pb[768 + t + 512] = so2;
  pb[1536 + t] = xt0;   pb[1536 + t + 256] = xt1;   pb[1536 + t + 512] = xt2;
  pb[2304 + t] = xo0;   pb[2304 + t + 256] = xo1;   pb[2304 + t + 512] = xo2;
}

// Pool stage B: combine 32 chunks -> pooled [B][4*768]
__global__ __launch_bounds__(256) void pool_final(const float* __restrict__ part,
                                                  float* __restrict__ pooled)
{
  const int idx = blockIdx.x * 256 + threadIdx.x;  // < B*D
  const int b = idx / DD, d = idx - b * DD;
  float st = 0, so = 0, xt = -3.4e38f, xo = -3.4e38f;
  for (int ch = 0; ch < 32; ch++) {
    const float* pb = part + (size_t)(b * 32 + ch) * 3072;
    st += pb[d]; so += pb[768 + d];
    xt = fmaxf(xt, pb[1536 + d]); xo = fmaxf(xo, pb[2304 + d]);
  }
  const float inv = 1.0f / (float)SS;
  pooled[(size_t)b * 3072 + d]        = st * inv;
  pooled[(size_t)b * 3072 + 768 + d]  = so * inv;
  pooled[(size_t)b * 3072 + 1536 + d] = xt;
  pooled[(size_t)b * 3072 + 2304 + d] = xo;
}

__global__ __launch_bounds__(256) void fc_k(const float* __restrict__ pooled,
                                            const float* __restrict__ Wf,
                                            const float* __restrict__ bf,
                                            float* __restrict__ outp)
{
  const int b = blockIdx.x, t = threadIdx.x;
  float p0 = 0.0f, p1 = 0.0f;
  #pragma unroll
  for (int i = 0; i < 12; i++) {
    const int j = t + i * 256;
    const float pv = pooled[(size_t)b * 3072 + j];
    p0 += pv * Wf[j * 2];
    p1 += pv * Wf[j * 2 + 1];
  }
  __shared__ float r0[256], r1[256];
  r0[t] = p0; r1[t] = p1; __syncthreads();
  #pragma unroll
  for (int off = 128; off > 0; off >>= 1) {
    if (t < off) { r0[t] += r0[t + off]; r1[t] += r1[t + off]; }
    __syncthreads();
  }
  if (t == 0) {
    outp[b * 2 + 0] = r0[0] + bf[0];
    outp[b * 2 + 1] = r1[0] + bf[1];
  }
}

// ---------------------------------------------------------------------------
// Host orchestration. fp16 GEMM I/O, fp32 softmax/LN/pool chain.
// Region map (byte offsets), peak ~202 MB:
//   R0 @ 0         (67.1MB f32): scores -> OUT -> attN_sc -> outN
//   R1 @ 67108864  (25.2MB f16): tokens_h -> out_ln_h -> attNT_h
//   R2 @ 92274688  (25.2MB f16): K_h -> KtN_h      (plane 0 of proj out)
//   R3 @ 117440512 (25.2MB f16): Q_h -> QtN_h      (plane 1)
//   R4 @ 142606336 (25.2MB f16): Vt_h -> VN_h      (plane 2)
//   R5 @ 167772160 (33.6MB f16): att_h -> attN_h
//   Wt @ 201326592 (3.5MB f16):  [3][768*768]
// ---------------------------------------------------------------------------
extern "C" void kernel_launch(void* const* d_in, const int* in_sizes, int n_in,
                              void* d_out, int out_size, void* d_ws, size_t ws_size,
                              hipStream_t stream)
{
  const float* tokens = (const float*)d_in[0];
  const float* Wk  = (const float*)d_in[1];
  const float* bk  = (const float*)d_in[2];
  const float* Wq  = (const float*)d_in[3];
  const float* bq  = (const float*)d_in[4];
  const float* Wv  = (const float*)d_in[5];
  const float* bv  = (const float*)d_in[6];
  const float* lng = (const float*)d_in[7];
  const float* lnb = (const float*)d_in[8];
  const float* Wsg = (const float*)d_in[9];
  const float* bsg = (const float*)d_in[10];
  const float* Wf  = (const float*)d_in[11];
  const float* bfn = (const float*)d_in[12];
  float* outp = (float*)d_out;
  (void)in_sizes; (void)n_in; (void)out_size; (void)ws_size;

  char* ws = (char*)d_ws;
  float*    R0   = (float*)(ws + 0);
  _Float16* R1   = (_Float16*)(ws + 67108864);
  _Float16* R2   = (_Float16*)(ws + 92274688);
  _Float16* R3   = (_Float16*)(ws + 117440512);
  _Float16* R4   = (_Float16*)(ws + 142606336);
  _Float16* R5   = (_Float16*)(ws + 167772160);
  _Float16* Wt   = (_Float16*)(ws + 201326592);   // 3,538,944 B
  float* bias3   = (float*)(ws + 204865536);      // 9,216 B
  float* part    = (float*)(ws + 204874752);      // 8,192 B
  float* stats   = (float*)(ws + 204882944);      // 128 B
  float* gate    = (float*)(ws + 204883072);      // 65,536 B
  float* ppart   = (float*)(ws + 204948608);      // 6,291,456 B
  float* pooled  = (float*)(ws + 211240064);      // 196,608 B (end ~201.7MB)

  const float fact = 0.036084391824351615f;  // 1/sqrt(768)
  const long long SD = (long long)SS * DD;   // 786432
  const long long S2 = (long long)SS * SS;   // 1048576
  const long long D2 = (long long)DD * DD;   // 589824
  const long long PL = (long long)BB * SD;   // 12582912 (one K/Q/V plane)

  // 1. casts / packing
  cast_f2h<<<2048, 256, 0, stream>>>(tokens, R1, PL / 4);
  transpose_f2h<<<dim3(24, 24), 256, 0, stream>>>(Wk, Wt,               768, 768);
  transpose_f2h<<<dim3(24, 24), 256, 0, stream>>>(Wq, Wt + 589824,      768, 768);
  transpose_f2h<<<dim3(24, 24), 256, 0, stream>>>(Wv, Wt + 2 * 589824,  768, 768);
  pack_bias<<<9, 256, 0, stream>>>(bk, bq, bv, bias3);

  // 2. Stage-1 projections, one launch: z0=K (R2), z1=Q (R3), z2=Vt (R4, transposed)
  gemm256<3, 1><<<dim3(64, 3, 3), 512, 0, stream>>>(R1, 0, Wt, 589824, bias3, 768,
                                                    (void*)R2, PL, BB * SS, DD, DD);
  // 3. scores = Q.K^T -> R0 fp32 [B,S,S]
  gemm256<0, 0><<<dim3(4, 4, 16), 512, 0, stream>>>(R3, SD, R2, SD, nullptr, 0,
                                                    (void*)R0, S2, SS, SS, DD);
  // 4. att_h = softmax(scores*fact) -> R5 fp16
  softmax_f2h<4><<<BB * SS, 256, 0, stream>>>(R0, R5, SS, fact);
  // 5. OUT = att @ V -> R0 fp32 [B,S,D]
  gemm256<0, 0><<<dim3(4, 3, 16), 512, 0, stream>>>(R5, S2, R4, SD, nullptr, 0,
                                                    (void*)R0, SD, SS, DD, SS);
  // 6. LayerNorm over (S,D) per batch: stats from fp32, out_ln_h -> R1 fp16
  ln_partial<<<dim3(64, 16), 256, 0, stream>>>(R0, part);
  ln_final<<<16, 64, 0, stream>>>(part, stats);
  ln_apply_h<<<2048, 256, 0, stream>>>(R0, lng, lnb, stats, R1);

  // 7. Stage-2 projections: z0=KtN (R2, tr), z1=QtN (R3, tr), z2=VN (R4, row-major)
  gemm256<4, 1><<<dim3(64, 3, 3), 512, 0, stream>>>(R1, 0, Wt, 589824, bias3, 768,
                                                    (void*)R2, PL, BB * SS, DD, DD);
  // 8. attN_sc[b,d,e] = QtN .NT. KtN -> R0 fp32 [B,D,D]
  gemm256<0, 0><<<dim3(3, 3, 16), 512, 0, stream>>>(R3, SD, R2, SD, nullptr, 0,
                                                    (void*)R0, D2, DD, DD, SS);
  // 9. attN_h = softmax -> R5 fp16
  softmax_f2h<3><<<BB * DD, 256, 0, stream>>>(R0, R5, DD, fact);
  // 10. attNT_h -> R1 (out_ln dead)
  transpose_b2h<<<dim3(24, 24, 16), 256, 0, stream>>>(R5, D2, R1, D2, DD, DD);
  // 11. outN = VN .NT. attNT -> R0 fp32 [B,S,D]
  gemm256<0, 0><<<dim3(4, 3, 16), 512, 0, stream>>>(R4, SD, R1, D2, nullptr, 0,
                                                    (void*)R0, SD, SS, DD, DD);

  // 12. gate, two-stage pooling, FC
  gate_k<<<4096, 256, 0, stream>>>(R0, Wsg, bsg, gate);
  pool_partial<<<dim3(32, BB), 256, 0, stream>>>(tokens, R0, gate, ppart);
  pool_final<<<48, 256, 0, stream>>>(ppart, pooled);
  fc_k<<<16, 256, 0, stream>>>(pooled, Wf, bfn, outp);
}

// Round 7
// 451.806 us; speedup vs baseline: 1.3318x; 1.0114x over previous
//
#include <hip/hip_runtime.h>

// Problem constants
#define BB 16
#define SS 1024
#define DD 768

typedef _Float16 f16x4 __attribute__((ext_vector_type(4)));
typedef _Float16 f16x8 __attribute__((ext_vector_type(8)));
typedef float f32x4 __attribute__((ext_vector_type(4)));

__device__ __forceinline__ void gload_lds16(const void* g, void* l) {
  __builtin_amdgcn_global_load_lds(
      (const __attribute__((address_space(1))) unsigned int*)g,
      (__attribute__((address_space(3))) unsigned int*)l, 16, 0, 0);
}

// ---------------------------------------------------------------------------
// 256x256 NT GEMM, 4-phase/K-tile pipelined (T3+T4+T5). fp16 in, fp32 acc.
// C[z][m][n] = sum_k A[z][m][k] * Bt[z][n][k] (+ bias[z][n])
// 512 threads = 8 waves (2M x 4N), per-wave 128x64 out (8x4 frags), BK=64.
//
// LDS: 2 dbuf sides x {A,B} x 2 k-slabs x 16KB = 128 KiB.
// Slab layout: [128 pairs][8 slots x 16B]. Element (row R, k-chunk c) of the
// slab lives at pair P=R>>1, slot q = ((R&1)<<2) | (c ^ (P&3)).
//   Bank group = q alone (P*128 = 0 mod 32 banks), so an octet of fragment
//   readers (lrow 0-7, fixed kq) hits q = {0,4,1,5,2,6,3,7} - all 8 groups,
//   zero conflict; a 16-lane quarter is 2-way (free, m136).
//   Staging (inverse, same involution): thread t -> P=t>>3, q=t&7:
//   src row 2(t>>3)+(q>>2), chunk (q&3)^((t>>3)&3); 16B within the row's
//   64B slab segment -> wave covers 16 full 64B segments (coalesced).
//   Dest stays linear (t*16, +8192 for rows 128-255; (P+64)&3 == P&3).
//
// Schedule per tile T (sides: sd = T&1 read, sn = sd^1 written):
//   p0: vmcnt(4); barrier; stage A-s0(T+1); read B-s0 + A-s0(m-half0); 16 MFMA
//   p1:           barrier; stage B-s0(T+1); read A-s0(m-half1);        16 MFMA
//   p2: vmcnt(4/0); barrier; stage A-s1(T+1); read B-s1 + A-s1(m0);    16 MFMA
//   p3:           barrier; stage B-s1(T+1); read A-s1(m1);             16 MFMA
// vmcnt(4): loads retire oldest-first; at p0 the 4 oldest outstanding are
// exactly {A-s0,B-s0}(T); at p2 {A-s1,B-s1}(T). (verified round 6)
//
// OUTM: 0 = fp32 row-major; 3 = f16, z<2 row-major / z==2 transposed;
//       4 = f16, z<2 transposed / z==2 row-major. Transposed = per-1024-row
//       batch: C[z][(b*N+c)*1024 + s], b=row>>10, s=row&1023.
// OUTM 3/4 (projection launches, shared A across z): grid is (9, M/256) and
// decoded as z = bx/3, n-tile = bx%3, m-tile = by -> 9 consecutive blocks
// share one A-tile (L2 reuse).
// ---------------------------------------------------------------------------
template<int OUTM, int BIAS>
__global__ __launch_bounds__(512) void gemm256(
    const _Float16* __restrict__ A, long long aB,
    const _Float16* __restrict__ Bt, long long bB,
    const float* __restrict__ bias, int biasB,
    void* __restrict__ Cv, long long cB,
    int M, int N, int K)
{
  __shared__ __attribute__((aligned(16))) _Float16 lds[65536];  // 128 KiB
  const int t = threadIdx.x;
  int z, m0, n0;
  if (OUTM == 3 || OUTM == 4) {           // projection decode: A shared over z
    z = blockIdx.x / 3;
    n0 = (blockIdx.x % 3) * 256;
    m0 = blockIdx.y * 256;
  } else {
    z = blockIdx.z;
    m0 = blockIdx.x * 256;
    n0 = blockIdx.y * 256;
  }
  const _Float16* Ab = A + (size_t)z * aB;
  const _Float16* Bb = Bt + (size_t)z * bB;

  const int l = t & 63, w = t >> 6;
  const int wr = (w >> 2) * 128, wc = (w & 3) * 64;
  const int lrow = l & 15, kq = l >> 4;
  // read-side swizzle (lane-constant): fragment (tile-row RB+lrow, chunk kq)
  // at byte RB*64 + fragoff   (RB multiple of 16 -> P&3 = (lrow>>1)&3)
  const int p2 = lrow >> 1;
  const int qread = ((lrow & 1) << 2) | (kq ^ (p2 & 3));
  const int fragoff = p2 * 128 + qread * 16;

  // staging lane constants (inverse of the same involution)
  const int sp = t >> 3, sq = t & 7;
  const int srow = 2 * sp + (sq >> 2);
  const int schk = (sq & 3) ^ (sp & 3);
  const size_t ldK = (size_t)K * 2;
  const char* pA0 = (const char*)Ab + (size_t)(m0 + srow) * ldK + schk * 16;
  const char* pA1 = pA0 + (size_t)128 * ldK;
  const char* pB0 = (const char*)Bb + (size_t)(n0 + srow) * ldK + schk * 16;
  const char* pB1 = pB0 + (size_t)128 * ldK;
  char* const ldsb = (char*)lds;
  const int dstt = t * 16;

  // stage one 16KB unit (mat: 0=A,1=B; k-slab s) of K-tile T into side sd
  auto stg = [&](int mat, int s, int T, int sd) {
    const char* g0 = (mat ? pB0 : pA0) + (size_t)T * 128 + s * 64;
    const char* g1 = (mat ? pB1 : pA1) + (size_t)T * 128 + s * 64;
    char* d = ldsb + sd * 65536 + mat * 32768 + s * 16384 + dstt;
    gload_lds16(g0, d);
    gload_lds16(g1, d + 8192);
  };

  f32x4 acc[8][4] = {};
  f16x8 af[4], bfr[4];

#define LOAD_B(S) { _Pragma("unroll") for (int n = 0; n < 4; n++) \
    bfr[n] = *(const f16x8*)(Bbase + (S) * 16384 + (wc + n * 16) * 64 + fragoff); }
#define LOAD_A(S, QM) { _Pragma("unroll") for (int mi = 0; mi < 4; mi++) \
    af[mi] = *(const f16x8*)(Abase + (S) * 16384 + (wr + (QM) * 64 + mi * 16) * 64 + fragoff); }
#define MFMA16(QM) { __builtin_amdgcn_s_setprio(1); \
    _Pragma("unroll") for (int mi = 0; mi < 4; mi++) { \
      _Pragma("unroll") for (int n = 0; n < 4; n++) \
        acc[(QM) * 4 + mi][n] = __builtin_amdgcn_mfma_f32_16x16x32_f16( \
            af[mi], bfr[n], acc[(QM) * 4 + mi][n], 0, 0, 0); } \
    __builtin_amdgcn_s_setprio(0); }

  // prologue: tile 0 -> side 0 (issue order = steady-state order)
  stg(0, 0, 0, 0); stg(1, 0, 0, 0); stg(0, 1, 0, 0); stg(1, 1, 0, 0);

  const int NT = K >> 6;
  for (int T = 0; T < NT; ++T) {
    const int sd = T & 1, sn = sd ^ 1;
    const char* Abase = ldsb + sd * 65536;
    const char* Bbase = Abase + 32768;
    const bool pf = (T + 1) < NT;

    // ---- phase 0: slab 0, m-half 0
    asm volatile("s_waitcnt vmcnt(4)" ::: "memory");
    __builtin_amdgcn_s_barrier();
    asm volatile("" ::: "memory");
    if (pf) stg(0, 0, T + 1, sn);
    LOAD_B(0)
    LOAD_A(0, 0)
    MFMA16(0)
    // ---- phase 1: slab 0, m-half 1
    __builtin_amdgcn_s_barrier();
    asm volatile("" ::: "memory");
    if (pf) stg(1, 0, T + 1, sn);
    LOAD_A(0, 1)
    MFMA16(1)
    // ---- phase 2: slab 1, m-half 0
    if (pf) asm volatile("s_waitcnt vmcnt(4)" ::: "memory");
    else    asm volatile("s_waitcnt vmcnt(0)" ::: "memory");
    __builtin_amdgcn_s_barrier();
    asm volatile("" ::: "memory");
    if (pf) stg(0, 1, T + 1, sn);
    LOAD_B(1)
    LOAD_A(1, 0)
    MFMA16(0)
    // ---- phase 3: slab 1, m-half 1
    __builtin_amdgcn_s_barrier();
    asm volatile("" ::: "memory");
    if (pf) stg(1, 1, T + 1, sn);
    LOAD_A(1, 1)
    MFMA16(1)
  }
#undef LOAD_A
#undef LOAD_B
#undef MFMA16

  // Epilogue. C/D layout: col = lane&15, row = 4*(lane>>4)+j.
  // acc[m] covers row wr + (m>>2)*64 + (m&3)*16.
  const int crow = (l >> 4) * 4, ccol = l & 15;
  #pragma unroll
  for (int m = 0; m < 8; ++m) {
    const int rq = m0 + wr + (m >> 2) * 64 + (m & 3) * 16 + crow;
    #pragma unroll
    for (int n = 0; n < 4; ++n) {
      const int c = n0 + wc + n * 16 + ccol;
      const float bv = BIAS ? bias[(size_t)z * biasB + c] : 0.0f;
      if (OUTM == 0) {
        float* C = (float*)Cv + (size_t)z * cB;
        #pragma unroll
        for (int j = 0; j < 4; j++)
          C[(size_t)(rq + j) * N + c] = acc[m][n][j] + bv;
      } else {
        _Float16* C = (_Float16*)Cv + (size_t)z * cB;
        const bool tr = (OUTM == 3) ? (z == 2) : (z < 2);
        if (tr) {
          const int bq = rq >> 10, s = rq & 1023;
          f16x4 o;
          #pragma unroll
          for (int j = 0; j < 4; j++) o[j] = (_Float16)(acc[m][n][j] + bv);
          *(f16x4*)&C[((size_t)(bq * N + c) << 10) + s] = o;
        } else {
          #pragma unroll
          for (int j = 0; j < 4; j++)
            C[(size_t)(rq + j) * N + c] = (_Float16)(acc[m][n][j] + bv);
        }
      }
    }
  }
}

// fp32 -> fp16 elementwise cast
__global__ __launch_bounds__(256) void cast_f2h(const float* __restrict__ in,
                                                _Float16* __restrict__ outp, long long n4)
{
  for (long long i = (long long)blockIdx.x * 256 + threadIdx.x; i < n4;
       i += (long long)gridDim.x * 256) {
    float4 v = ((const float4*)in)[i];
    f16x4 r;
    r[0] = (_Float16)v.x; r[1] = (_Float16)v.y; r[2] = (_Float16)v.z; r[3] = (_Float16)v.w;
    ((f16x4*)outp)[i] = r;
  }
}

// fp32 [R][C] -> fp16 [C][R] (weights transpose+cast)
__global__ __launch_bounds__(256) void transpose_f2h(const float* __restrict__ in,
                                                     _Float16* __restrict__ outp, int R, int C)
{
  __shared__ float tile[32][33];
  const int r0 = blockIdx.y * 32, c0 = blockIdx.x * 32;
  const int tx = threadIdx.x & 31, ty = threadIdx.x >> 5;  // 32 x 8
  #pragma unroll
  for (int i = 0; i < 4; i++)
    tile[ty + i * 8][tx] = in[(size_t)(r0 + ty + i * 8) * C + c0 + tx];
  __syncthreads();
  #pragma unroll
  for (int i = 0; i < 4; i++)
    outp[(size_t)(c0 + ty + i * 8) * R + r0 + tx] = (_Float16)tile[tx][ty + i * 8];
}

// fp16 [R][C] -> [C][R], batched over blockIdx.z
__global__ __launch_bounds__(256) void transpose_b2h(const _Float16* __restrict__ in, long long inB,
                                                     _Float16* __restrict__ outp, long long outB,
                                                     int R, int C)
{
  __shared__ _Float16 tile[32][33];
  const _Float16* ib = in + (size_t)blockIdx.z * inB;
  _Float16* ob = outp + (size_t)blockIdx.z * outB;
  const int r0 = blockIdx.y * 32, c0 = blockIdx.x * 32;
  const int tx = threadIdx.x & 31, ty = threadIdx.x >> 5;
  #pragma unroll
  for (int i = 0; i < 4; i++)
    tile[ty + i * 8][tx] = ib[(size_t)(r0 + ty + i * 8) * C + c0 + tx];
  __syncthreads();
  #pragma unroll
  for (int i = 0; i < 4; i++)
    ob[(size_t)(c0 + ty + i * 8) * R + r0 + tx] = tile[tx][ty + i * 8];
}

__global__ void pack_bias(const float* __restrict__ a, const float* __restrict__ b,
                          const float* __restrict__ c, float* __restrict__ o)
{
  int t = blockIdx.x * 256 + threadIdx.x;
  if (t < 768) o[t] = a[t];
  else if (t < 1536) o[t] = b[t - 768];
  else if (t < 2304) o[t] = c[t - 1536];
}

// Row softmax: fp32 in, fp16 out. L = VPT*256.
template<int VPT>
__global__ __launch_bounds__(256) void softmax_f2h(const float* __restrict__ X,
                                                   _Float16* __restrict__ Y,
                                                   int L, float scale)
{
  const size_t base = (size_t)blockIdx.x * L;
  const int t = threadIdx.x;
  float v[VPT];
  float m = -3.4e38f;
  #pragma unroll
  for (int j = 0; j < VPT; j++) { v[j] = X[base + t + j * 256]; m = fmaxf(m, v[j]); }
  __shared__ float red[256];
  red[t] = m; __syncthreads();
  #pragma unroll
  for (int off = 128; off > 0; off >>= 1) {
    if (t < off) red[t] = fmaxf(red[t], red[t + off]);
    __syncthreads();
  }
  m = red[0]; __syncthreads();
  float s = 0.0f;
  #pragma unroll
  for (int j = 0; j < VPT; j++) { v[j] = __expf((v[j] - m) * scale); s += v[j]; }
  red[t] = s; __syncthreads();
  #pragma unroll
  for (int off = 128; off > 0; off >>= 1) {
    if (t < off) red[t] += red[t + off];
    __syncthreads();
  }
  const float inv = 1.0f / red[0];
  #pragma unroll
  for (int j = 0; j < VPT; j++) Y[base + t + j * 256] = (_Float16)(v[j] * inv);
}

// LayerNorm over (S,D) jointly per batch
__global__ __launch_bounds__(256) void ln_partial(const float* __restrict__ src,
                                                  float* __restrict__ part)
{
  const int b = blockIdx.y, ch = blockIdx.x;   // 64 chunks per batch
  const float4* p = (const float4*)(src + (size_t)b * SS * DD) + (size_t)ch * 3072;
  const int t = threadIdx.x;
  float s = 0.0f, q = 0.0f;
  #pragma unroll
  for (int i = 0; i < 12; i++) {
    float4 v = p[t + i * 256];
    s += v.x + v.y + v.z + v.w;
    q += v.x * v.x + v.y * v.y + v.z * v.z + v.w * v.w;
  }
  __shared__ float rs[256], rq[256];
  rs[t] = s; rq[t] = q; __syncthreads();
  #pragma unroll
  for (int off = 128; off > 0; off >>= 1) {
    if (t < off) { rs[t] += rs[t + off]; rq[t] += rq[t + off]; }
    __syncthreads();
  }
  if (t == 0) { part[(b * 64 + ch) * 2] = rs[0]; part[(b * 64 + ch) * 2 + 1] = rq[0]; }
}

__global__ void ln_final(const float* __restrict__ part, float* __restrict__ stats)
{
  const int b = blockIdx.x, t = threadIdx.x;  // 64 threads = 1 wave
  float s = part[(b * 64 + t) * 2];
  float q = part[(b * 64 + t) * 2 + 1];
  #pragma unroll
  for (int off = 32; off > 0; off >>= 1) { s += __shfl_down(s, off); q += __shfl_down(q, off); }
  if (t == 0) {
    const float invN = 1.0f / (float)(SS * DD);
    float mu = s * invN;
    float var = q * invN - mu * mu;
    stats[b * 2] = mu;
    stats[b * 2 + 1] = rsqrtf(var + 1e-8f);
  }
}

__global__ __launch_bounds__(256) void ln_apply_h(const float* __restrict__ src,
                                                  const float* __restrict__ g,
                                                  const float* __restrict__ bta,
                                                  const float* __restrict__ stats,
                                                  _Float16* __restrict__ dst)
{
  const long long n4 = (long long)BB * SS * DD / 4;
  const int SD4 = SS * DD / 4;
  for (long long i = (long long)blockIdx.x * 256 + threadIdx.x; i < n4;
       i += (long long)gridDim.x * 256) {
    const int b = (int)(i / SD4);
    const int sd4 = (int)(i - (long long)b * SD4);
    const float mu = stats[b * 2], rs = stats[b * 2 + 1];
    float4 v = ((const float4*)src)[i];
    float4 gg = ((const float4*)g)[sd4];
    float4 bb = ((const float4*)bta)[sd4];
    f16x4 r;
    r[0] = (_Float16)((v.x - mu) * rs * gg.x + bb.x);
    r[1] = (_Float16)((v.y - mu) * rs * gg.y + bb.y);
    r[2] = (_Float16)((v.z - mu) * rs * gg.z + bb.z);
    r[3] = (_Float16)((v.w - mu) * rs * gg.w + bb.w);
    ((f16x4*)dst)[i] = r;
  }
}

// gate[b,s] = dot(out_N[b,s,:], W_sgsa) + b_sgsa ; one wave per row
__global__ __launch_bounds__(256) void gate_k(const float* __restrict__ outN,
                                              const float* __restrict__ wsg,
                                              const float* __restrict__ bsg,
                                              float* __restrict__ gate)
{
  const int row = blockIdx.x * 4 + (threadIdx.x >> 6);
  const int l = threadIdx.x & 63;
  const float* src = outN + (size_t)row * DD;
  float s = 0.0f;
  #pragma unroll
  for (int i = 0; i < 12; i++) s += src[l + i * 64] * wsg[l + i * 64];
  #pragma unroll
  for (int off = 32; off > 0; off >>= 1) s += __shfl_down(s, off);
  if (l == 0) gate[row] = s + bsg[0];
}

// Pool stage A: grid (32 chunks, 16 batches); each block: 32 rows x 768 cols
__global__ __launch_bounds__(256) void pool_partial(const float* __restrict__ tokens,
                                                    const float* __restrict__ outN,
                                                    const float* __restrict__ gate,
                                                    float* __restrict__ part)
{
  const int b = blockIdx.y, ch = blockIdx.x, t = threadIdx.x;
  float st0 = 0, st1 = 0, st2 = 0, so0 = 0, so1 = 0, so2 = 0;
  float xt0 = -3.4e38f, xt1 = -3.4e38f, xt2 = -3.4e38f;
  float xo0 = -3.4e38f, xo1 = -3.4e38f, xo2 = -3.4e38f;
  const size_t rowbase = ((size_t)b * SS + ch * 32) * DD;
  for (int i = 0; i < 32; i++) {
    const float* tr = tokens + rowbase + (size_t)i * DD;
    const float* orw = outN + rowbase + (size_t)i * DD;
    const float g = gate[b * SS + ch * 32 + i];
    float t0 = tr[t], t1 = tr[t + 256], t2 = tr[t + 512];
    float o0 = orw[t] * g, o1 = orw[t + 256] * g, o2 = orw[t + 512] * g;
    st0 += t0; st1 += t1; st2 += t2;
    so0 += o0; so1 += o1; so2 += o2;
    xt0 = fmaxf(xt0, t0); xt1 = fmaxf(xt1, t1); xt2 = fmaxf(xt2, t2);
    xo0 = fmaxf(xo0, o0); xo1 = fmaxf(xo1, o1); xo2 = fmaxf(xo2, o2);
  }
  float* pb = part + (size_t)(b * 32 + ch) * 3072;
  pb[t] = st0;          pb[t + 256] = st1;          pb[t + 512] = st2;
  pb[768 + t] = so0;    pb[768 + t + 256] = so1;    pb[768 + t + 512] = so2;
  pb[1536 + t] = xt0;   pb[1536 + t + 256] = xt1;   pb[1536 + t + 512] = xt2;
  pb[2304 + t] = xo0;   pb[2304 + t + 256] = xo1;   pb[2304 + t + 512] = xo2;
}

// Pool stage B: combine 32 chunks -> pooled [B][4*768]
__global__ __launch_bounds__(256) void pool_final(const float* __restrict__ part,
                                                  float* __restrict__ pooled)
{
  const int idx = blockIdx.x * 256 + threadIdx.x;  // < B*D
  const int b = idx / DD, d = idx - b * DD;
  float st = 0, so = 0, xt = -3.4e38f, xo = -3.4e38f;
  for (int ch = 0; ch < 32; ch++) {
    const float* pb = part + (size_t)(b * 32 + ch) * 3072;
    st += pb[d]; so += pb[768 + d];
    xt = fmaxf(xt, pb[1536 + d]); xo = fmaxf(xo, pb[2304 + d]);
  }
  const float inv = 1.0f / (float)SS;
  pooled[(size_t)b * 3072 + d]        = st * inv;
  pooled[(size_t)b * 3072 + 768 + d]  = so * inv;
  pooled[(size_t)b * 3072 + 1536 + d] = xt;
  pooled[(size_t)b * 3072 + 2304 + d] = xo;
}

__global__ __launch_bounds__(256) void fc_k(const float* __restrict__ pooled,
                                            const float* __restrict__ Wf,
                                            const float* __restrict__ bf,
                                            float* __restrict__ outp)
{
  const int b = blockIdx.x, t = threadIdx.x;
  float p0 = 0.0f, p1 = 0.0f;
  #pragma unroll
  for (int i = 0; i < 12; i++) {
    const int j = t + i * 256;
    const float pv = pooled[(size_t)b * 3072 + j];
    p0 += pv * Wf[j * 2];
    p1 += pv * Wf[j * 2 + 1];
  }
  __shared__ float r0[256], r1[256];
  r0[t] = p0; r1[t] = p1; __syncthreads();
  #pragma unroll
  for (int off = 128; off > 0; off >>= 1) {
    if (t < off) { r0[t] += r0[t + off]; r1[t] += r1[t + off]; }
    __syncthreads();
  }
  if (t == 0) {
    outp[b * 2 + 0] = r0[0] + bf[0];
    outp[b * 2 + 1] = r1[0] + bf[1];
  }
}

// ---------------------------------------------------------------------------
// Host orchestration. fp16 GEMM I/O, fp32 softmax/LN/pool chain.
// Region map (byte offsets), peak ~202 MB:
//   R0 @ 0         (67.1MB f32): scores -> OUT -> attN_sc -> outN
//   R1 @ 67108864  (25.2MB f16): tokens_h -> out_ln_h -> attNT_h
//   R2 @ 92274688  (25.2MB f16): K_h -> KtN_h      (plane 0 of proj out)
//   R3 @ 117440512 (25.2MB f16): Q_h -> QtN_h      (plane 1)
//   R4 @ 142606336 (25.2MB f16): Vt_h -> VN_h      (plane 2)
//   R5 @ 167772160 (33.6MB f16): att_h -> attN_h
//   Wt @ 201326592 (3.5MB f16):  [3][768*768]
// ---------------------------------------------------------------------------
extern "C" void kernel_launch(void* const* d_in, const int* in_sizes, int n_in,
                              void* d_out, int out_size, void* d_ws, size_t ws_size,
                              hipStream_t stream)
{
  const float* tokens = (const float*)d_in[0];
  const float* Wk  = (const float*)d_in[1];
  const float* bk  = (const float*)d_in[2];
  const float* Wq  = (const float*)d_in[3];
  const float* bq  = (const float*)d_in[4];
  const float* Wv  = (const float*)d_in[5];
  const float* bv  = (const float*)d_in[6];
  const float* lng = (const float*)d_in[7];
  const float* lnb = (const float*)d_in[8];
  const float* Wsg = (const float*)d_in[9];
  const float* bsg = (const float*)d_in[10];
  const float* Wf  = (const float*)d_in[11];
  const float* bfn = (const float*)d_in[12];
  float* outp = (float*)d_out;
  (void)in_sizes; (void)n_in; (void)out_size; (void)ws_size;

  char* ws = (char*)d_ws;
  float*    R0   = (float*)(ws + 0);
  _Float16* R1   = (_Float16*)(ws + 67108864);
  _Float16* R2   = (_Float16*)(ws + 92274688);
  _Float16* R3   = (_Float16*)(ws + 117440512);
  _Float16* R4   = (_Float16*)(ws + 142606336);
  _Float16* R5   = (_Float16*)(ws + 167772160);
  _Float16* Wt   = (_Float16*)(ws + 201326592);   // 3,538,944 B
  float* bias3   = (float*)(ws + 204865536);      // 9,216 B
  float* part    = (float*)(ws + 204874752);      // 8,192 B
  float* stats   = (float*)(ws + 204882944);      // 128 B
  float* gate    = (float*)(ws + 204883072);      // 65,536 B
  float* ppart   = (float*)(ws + 204948608);      // 6,291,456 B
  float* pooled  = (float*)(ws + 211240064);      // 196,608 B (end ~201.7MB)

  const float fact = 0.036084391824351615f;  // 1/sqrt(768)
  const long long SD = (long long)SS * DD;   // 786432
  const long long S2 = (long long)SS * SS;   // 1048576
  const long long D2 = (long long)DD * DD;   // 589824
  const long long PL = (long long)BB * SD;   // 12582912 (one K/Q/V plane)

  // 1. casts / packing
  cast_f2h<<<2048, 256, 0, stream>>>(tokens, R1, PL / 4);
  transpose_f2h<<<dim3(24, 24), 256, 0, stream>>>(Wk, Wt,               768, 768);
  transpose_f2h<<<dim3(24, 24), 256, 0, stream>>>(Wq, Wt + 589824,      768, 768);
  transpose_f2h<<<dim3(24, 24), 256, 0, stream>>>(Wv, Wt + 2 * 589824,  768, 768);
  pack_bias<<<9, 256, 0, stream>>>(bk, bq, bv, bias3);

  // 2. Stage-1 projections, one launch: z0=K (R2), z1=Q (R3), z2=Vt (R4, transposed)
  gemm256<3, 1><<<dim3(9, 64, 1), 512, 0, stream>>>(R1, 0, Wt, 589824, bias3, 768,
                                                    (void*)R2, PL, BB * SS, DD, DD);
  // 3. scores = Q.K^T -> R0 fp32 [B,S,S]
  gemm256<0, 0><<<dim3(4, 4, 16), 512, 0, stream>>>(R3, SD, R2, SD, nullptr, 0,
                                                    (void*)R0, S2, SS, SS, DD);
  // 4. att_h = softmax(scores*fact) -> R5 fp16
  softmax_f2h<4><<<BB * SS, 256, 0, stream>>>(R0, R5, SS, fact);
  // 5. OUT = att @ V -> R0 fp32 [B,S,D]
  gemm256<0, 0><<<dim3(4, 3, 16), 512, 0, stream>>>(R5, S2, R4, SD, nullptr, 0,
                                                    (void*)R0, SD, SS, DD, SS);
  // 6. LayerNorm over (S,D) per batch: stats from fp32, out_ln_h -> R1 fp16
  ln_partial<<<dim3(64, 16), 256, 0, stream>>>(R0, part);
  ln_final<<<16, 64, 0, stream>>>(part, stats);
  ln_apply_h<<<2048, 256, 0, stream>>>(R0, lng, lnb, stats, R1);

  // 7. Stage-2 projections: z0=KtN (R2, tr), z1=QtN (R3, tr), z2=VN (R4, row-major)
  gemm256<4, 1><<<dim3(9, 64, 1), 512, 0, stream>>>(R1, 0, Wt, 589824, bias3, 768,
                                                    (void*)R2, PL, BB * SS, DD, DD);
  // 8. attN_sc[b,d,e] = QtN .NT. KtN -> R0 fp32 [B,D,D]
  gemm256<0, 0><<<dim3(3, 3, 16), 512, 0, stream>>>(R3, SD, R2, SD, nullptr, 0,
                                                    (void*)R0, D2, DD, DD, SS);
  // 9. attN_h = softmax -> R5 fp16
  softmax_f2h<3><<<BB * DD, 256, 0, stream>>>(R0, R5, DD, fact);
  // 10. attNT_h -> R1 (out_ln dead)
  transpose_b2h<<<dim3(24, 24, 16), 256, 0, stream>>>(R5, D2, R1, D2, DD, DD);
  // 11. outN = VN .NT. attNT -> R0 fp32 [B,S,D]
  gemm256<0, 0><<<dim3(4, 3, 16), 512, 0, stream>>>(R4, SD, R1, D2, nullptr, 0,
                                                    (void*)R0, SD, SS, DD, DD);

  // 12. gate, two-stage pooling, FC
  gate_k<<<4096, 256, 0, stream>>>(R0, Wsg, bsg, gate);
  pool_partial<<<dim3(32, BB), 256, 0, stream>>>(tokens, R0, gate, ppart);
  pool_final<<<48, 256, 0, stream>>>(ppart, pooled);
  fc_k<<<16, 256, 0, stream>>>(pooled, Wf, bfn, outp);
}

// Round 8
// 441.119 us; speedup vs baseline: 1.3641x; 1.0242x over previous
//
#include <hip/hip_runtime.h>

// Problem constants
#define BB 16
#define SS 1024
#define DD 768

typedef _Float16 f16x4 __attribute__((ext_vector_type(4)));
typedef _Float16 f16x8 __attribute__((ext_vector_type(8)));
typedef float f32x4 __attribute__((ext_vector_type(4)));

__device__ __forceinline__ void gload_lds16(const void* g, void* l) {
  __builtin_amdgcn_global_load_lds(
      (const __attribute__((address_space(1))) unsigned int*)g,
      (__attribute__((address_space(3))) unsigned int*)l, 16, 0, 0);
}

// ---------------------------------------------------------------------------
// 256x256 NT GEMM, 2-region/K-tile pipelined (T3+T4+T5). fp16 in, fp32 acc.
// C[z][m][n] = sum_k A[z][m][k] * Bt[z][n][k] (+ bias[z][n])
// 512 threads = 8 waves (2M x 4N), per-wave 128x64 out (8x4 frags), BK=64.
//
// LDS: 2 dbuf sides x {A,B} x 2 k-slabs x 16KB = 128 KiB.
// Slab layout: [128 pairs][8 slots x 16B]. Element (row R, k-chunk c) of the
// slab lives at pair P=R>>1, slot q = ((R&1)<<2) | (c ^ (P&3)).
//   Bank group = q alone (P*128 = 0 mod 32 banks): an octet of fragment
//   readers (lrow 0-7, fixed kq) hits all 8 groups -> zero conflict; a
//   16-lane quarter is 2-way (free). (verified round 7: BANK_CONFLICT = 0)
//   Staging (inverse involution): thread t -> src row 2(t>>3)+((t&7)>>2),
//   chunk ((t&3))^((t>>3)&3); dest linear t*16 (+8192 for rows 128-255).
//   Wave covers 16 full 64B segments -> coalesced.
//
// Schedule per tile T (sd = T&1 read side, sn = sd^1 write side), 2 regions:
//   R0: vmcnt(4); barrier; stage {A,B}-s0(T+1)->sn; read slab0 (12xb128,
//       3 independent reg sets); 32 MFMA   (compiler interleaves freely)
//   R1: vmcnt(4) [0 on last]; barrier; stage {A,B}-s1(T+1)->sn; read slab1;
//       32 MFMA
// vmcnt proof (in-order retirement): at R0 entry outstanding = T's 8 loads
// -> vmcnt(4) retires {A,B}-s0(T). After R0's stage, outstanding = T-s1(4)
// + (T+1)-s0(4); at R1 vmcnt(4) retires T-s1. At next R0: outstanding =
// (T+1)'s 8. Steady. Each {vmcnt; barrier} publishes ALL waves' staged data
// (each wave waits its own loads, then barrier). WAR on sn: all tile-T-1
// reads of sn retired before their MFMAs, hence before T's R0 barrier.
//
// OUTM: 0 = fp32 row-major; 3 = f16, z<2 row-major / z==2 transposed;
//       4 = f16, z<2 transposed / z==2 row-major. Transposed = per-1024-row
//       batch: C[z][(b*N+c)*1024 + s], b=row>>10, s=row&1023.
// OUTM 3/4 (projections, A shared over z): grid (9, 64); XCD-aware decode
// puts all 9 blocks of one m-tile on ONE XCD (lin%8 const) so the A-tile is
// fetched once per XCD L2 (round-7 lesson: consecutive blocks round-robin
// across XCDs, private L2s re-fetch).
// ---------------------------------------------------------------------------
template<int OUTM, int BIAS>
__global__ __launch_bounds__(512) void gemm256(
    const _Float16* __restrict__ A, long long aB,
    const _Float16* __restrict__ Bt, long long bB,
    const float* __restrict__ bias, int biasB,
    void* __restrict__ Cv, long long cB,
    int M, int N, int K)
{
  __shared__ __attribute__((aligned(16))) _Float16 lds[65536];  // 128 KiB
  const int t = threadIdx.x;
  int z, m0, n0;
  if (OUTM == 3 || OUTM == 4) {     // projection decode, XCD-grouped
    const int lin = blockIdx.x + 9 * blockIdx.y;   // 0..575
    const int xcd = lin & 7, idx = lin >> 3;       // idx 0..71
    const int mt  = xcd * 8 + idx / 9;
    const int zn  = idx % 9;
    z  = zn / 3;
    n0 = (zn % 3) * 256;
    m0 = mt * 256;
  } else {
    z = blockIdx.z;
    m0 = blockIdx.x * 256;
    n0 = blockIdx.y * 256;
  }
  const _Float16* Ab = A + (size_t)z * aB;
  const _Float16* Bb = Bt + (size_t)z * bB;

  const int l = t & 63, w = t >> 6;
  const int wr = (w >> 2) * 128, wc = (w & 3) * 64;
  const int lrow = l & 15, kq = l >> 4;
  // read-side swizzle (lane-constant)
  const int p2 = lrow >> 1;
  const int qread = ((lrow & 1) << 2) | (kq ^ (p2 & 3));
  const int fragoff = p2 * 128 + qread * 16;

  // staging lane constants (inverse of the same involution)
  const int sp = t >> 3, sq = t & 7;
  const int srow = 2 * sp + (sq >> 2);
  const int schk = (sq & 3) ^ (sp & 3);
  const size_t ldK = (size_t)K * 2;
  const char* pA0 = (const char*)Ab + (size_t)(m0 + srow) * ldK + schk * 16;
  const char* pA1 = pA0 + (size_t)128 * ldK;
  const char* pB0 = (const char*)Bb + (size_t)(n0 + srow) * ldK + schk * 16;
  const char* pB1 = pB0 + (size_t)128 * ldK;
  char* const ldsb = (char*)lds;
  const int dstt = t * 16;

  // stage one 16KB unit (mat: 0=A,1=B; k-slab s) of K-tile T into side sd
  auto stg = [&](int mat, int s, int T, int sd) {
    const char* g0 = (mat ? pB0 : pA0) + (size_t)T * 128 + s * 64;
    const char* g1 = (mat ? pB1 : pA1) + (size_t)T * 128 + s * 64;
    char* d = ldsb + sd * 65536 + mat * 32768 + s * 16384 + dstt;
    gload_lds16(g0, d);
    gload_lds16(g1, d + 8192);
  };

  f32x4 acc[8][4] = {};
  f16x8 a0f[4], a1f[4], bfr[4];   // 3 independent reg sets per region

#define LOAD_B(S) { _Pragma("unroll") for (int n = 0; n < 4; n++) \
    bfr[n] = *(const f16x8*)(Bbase + (S) * 16384 + (wc + n * 16) * 64 + fragoff); }
#define LOAD_A0(S) { _Pragma("unroll") for (int mi = 0; mi < 4; mi++) \
    a0f[mi] = *(const f16x8*)(Abase + (S) * 16384 + (wr + mi * 16) * 64 + fragoff); }
#define LOAD_A1(S) { _Pragma("unroll") for (int mi = 0; mi < 4; mi++) \
    a1f[mi] = *(const f16x8*)(Abase + (S) * 16384 + (wr + 64 + mi * 16) * 64 + fragoff); }
#define MFMA32 { __builtin_amdgcn_s_setprio(1); \
    _Pragma("unroll") for (int mi = 0; mi < 4; mi++) { \
      _Pragma("unroll") for (int n = 0; n < 4; n++) \
        acc[mi][n] = __builtin_amdgcn_mfma_f32_16x16x32_f16( \
            a0f[mi], bfr[n], acc[mi][n], 0, 0, 0); } \
    _Pragma("unroll") for (int mi = 0; mi < 4; mi++) { \
      _Pragma("unroll") for (int n = 0; n < 4; n++) \
        acc[4 + mi][n] = __builtin_amdgcn_mfma_f32_16x16x32_f16( \
            a1f[mi], bfr[n], acc[4 + mi][n], 0, 0, 0); } \
    __builtin_amdgcn_s_setprio(0); }

  // prologue: tile 0 -> side 0 (retirement order = {A,B}-s0, {A,B}-s1)
  stg(0, 0, 0, 0); stg(1, 0, 0, 0); stg(0, 1, 0, 0); stg(1, 1, 0, 0);

  const int NT = K >> 6;
  for (int T = 0; T < NT; ++T) {
    const int sd = T & 1, sn = sd ^ 1;
    const char* Abase = ldsb + sd * 65536;
    const char* Bbase = Abase + 32768;
    const bool pf = (T + 1) < NT;

    // ---- region 0: k-slab 0
    asm volatile("s_waitcnt vmcnt(4)" ::: "memory");
    __builtin_amdgcn_s_barrier();
    asm volatile("" ::: "memory");
    if (pf) { stg(0, 0, T + 1, sn); stg(1, 0, T + 1, sn); }
    LOAD_B(0)
    LOAD_A0(0)
    LOAD_A1(0)
    MFMA32
    // ---- region 1: k-slab 1
    if (pf) asm volatile("s_waitcnt vmcnt(4)" ::: "memory");
    else    asm volatile("s_waitcnt vmcnt(0)" ::: "memory");
    __builtin_amdgcn_s_barrier();
    asm volatile("" ::: "memory");
    if (pf) { stg(0, 1, T + 1, sn); stg(1, 1, T + 1, sn); }
    LOAD_B(1)
    LOAD_A0(1)
    LOAD_A1(1)
    MFMA32
  }
#undef LOAD_B
#undef LOAD_A0
#undef LOAD_A1
#undef MFMA32

  // Epilogue. C/D layout: col = lane&15, row = 4*(lane>>4)+j.
  // acc[m] covers row wr + (m>>2)*64 + (m&3)*16.
  const int crow = (l >> 4) * 4, ccol = l & 15;
  #pragma unroll
  for (int m = 0; m < 8; ++m) {
    const int rq = m0 + wr + (m >> 2) * 64 + (m & 3) * 16 + crow;
    #pragma unroll
    for (int n = 0; n < 4; ++n) {
      const int c = n0 + wc + n * 16 + ccol;
      const float bv = BIAS ? bias[(size_t)z * biasB + c] : 0.0f;
      if (OUTM == 0) {
        float* C = (float*)Cv + (size_t)z * cB;
        #pragma unroll
        for (int j = 0; j < 4; j++)
          C[(size_t)(rq + j) * N + c] = acc[m][n][j] + bv;
      } else {
        _Float16* C = (_Float16*)Cv + (size_t)z * cB;
        const bool tr = (OUTM == 3) ? (z == 2) : (z < 2);
        if (tr) {
          const int bq = rq >> 10, s = rq & 1023;
          f16x4 o;
          #pragma unroll
          for (int j = 0; j < 4; j++) o[j] = (_Float16)(acc[m][n][j] + bv);
          *(f16x4*)&C[((size_t)(bq * N + c) << 10) + s] = o;
        } else {
          #pragma unroll
          for (int j = 0; j < 4; j++)
            C[(size_t)(rq + j) * N + c] = (_Float16)(acc[m][n][j] + bv);
        }
      }
    }
  }
}

// fp32 -> fp16 elementwise cast
__global__ __launch_bounds__(256) void cast_f2h(const float* __restrict__ in,
                                                _Float16* __restrict__ outp, long long n4)
{
  for (long long i = (long long)blockIdx.x * 256 + threadIdx.x; i < n4;
       i += (long long)gridDim.x * 256) {
    float4 v = ((const float4*)in)[i];
    f16x4 r;
    r[0] = (_Float16)v.x; r[1] = (_Float16)v.y; r[2] = (_Float16)v.z; r[3] = (_Float16)v.w;
    ((f16x4*)outp)[i] = r;
  }
}

// fp32 [R][C] -> fp16 [C][R] (weights transpose+cast)
__global__ __launch_bounds__(256) void transpose_f2h(const float* __restrict__ in,
                                                     _Float16* __restrict__ outp, int R, int C)
{
  __shared__ float tile[32][33];
  const int r0 = blockIdx.y * 32, c0 = blockIdx.x * 32;
  const int tx = threadIdx.x & 31, ty = threadIdx.x >> 5;  // 32 x 8
  #pragma unroll
  for (int i = 0; i < 4; i++)
    tile[ty + i * 8][tx] = in[(size_t)(r0 + ty + i * 8) * C + c0 + tx];
  __syncthreads();
  #pragma unroll
  for (int i = 0; i < 4; i++)
    outp[(size_t)(c0 + ty + i * 8) * R + r0 + tx] = (_Float16)tile[tx][ty + i * 8];
}

// fp16 [R][C] -> [C][R], batched over blockIdx.z
__global__ __launch_bounds__(256) void transpose_b2h(const _Float16* __restrict__ in, long long inB,
                                                     _Float16* __restrict__ outp, long long outB,
                                                     int R, int C)
{
  __shared__ _Float16 tile[32][33];
  const _Float16* ib = in + (size_t)blockIdx.z * inB;
  _Float16* ob = outp + (size_t)blockIdx.z * outB;
  const int r0 = blockIdx.y * 32, c0 = blockIdx.x * 32;
  const int tx = threadIdx.x & 31, ty = threadIdx.x >> 5;
  #pragma unroll
  for (int i = 0; i < 4; i++)
    tile[ty + i * 8][tx] = ib[(size_t)(r0 + ty + i * 8) * C + c0 + tx];
  __syncthreads();
  #pragma unroll
  for (int i = 0; i < 4; i++)
    ob[(size_t)(c0 + ty + i * 8) * R + r0 + tx] = tile[tx][ty + i * 8];
}

__global__ void pack_bias(const float* __restrict__ a, const float* __restrict__ b,
                          const float* __restrict__ c, float* __restrict__ o)
{
  int t = blockIdx.x * 256 + threadIdx.x;
  if (t < 768) o[t] = a[t];
  else if (t < 1536) o[t] = b[t - 768];
  else if (t < 2304) o[t] = c[t - 1536];
}

// Row softmax: fp32 in, fp16 out. L = VPT*256.
template<int VPT>
__global__ __launch_bounds__(256) void softmax_f2h(const float* __restrict__ X,
                                                   _Float16* __restrict__ Y,
                                                   int L, float scale)
{
  const size_t base = (size_t)blockIdx.x * L;
  const int t = threadIdx.x;
  float v[VPT];
  float m = -3.4e38f;
  #pragma unroll
  for (int j = 0; j < VPT; j++) { v[j] = X[base + t + j * 256]; m = fmaxf(m, v[j]); }
  __shared__ float red[256];
  red[t] = m; __syncthreads();
  #pragma unroll
  for (int off = 128; off > 0; off >>= 1) {
    if (t < off) red[t] = fmaxf(red[t], red[t + off]);
    __syncthreads();
  }
  m = red[0]; __syncthreads();
  float s = 0.0f;
  #pragma unroll
  for (int j = 0; j < VPT; j++) { v[j] = __expf((v[j] - m) * scale); s += v[j]; }
  red[t] = s; __syncthreads();
  #pragma unroll
  for (int off = 128; off > 0; off >>= 1) {
    if (t < off) red[t] += red[t + off];
    __syncthreads();
  }
  const float inv = 1.0f / red[0];
  #pragma unroll
  for (int j = 0; j < VPT; j++) Y[base + t + j * 256] = (_Float16)(v[j] * inv);
}

// LayerNorm over (S,D) jointly per batch
__global__ __launch_bounds__(256) void ln_partial(const float* __restrict__ src,
                                                  float* __restrict__ part)
{
  const int b = blockIdx.y, ch = blockIdx.x;   // 64 chunks per batch
  const float4* p = (const float4*)(src + (size_t)b * SS * DD) + (size_t)ch * 3072;
  const int t = threadIdx.x;
  float s = 0.0f, q = 0.0f;
  #pragma unroll
  for (int i = 0; i < 12; i++) {
    float4 v = p[t + i * 256];
    s += v.x + v.y + v.z + v.w;
    q += v.x * v.x + v.y * v.y + v.z * v.z + v.w * v.w;
  }
  __shared__ float rs[256], rq[256];
  rs[t] = s; rq[t] = q; __syncthreads();
  #pragma unroll
  for (int off = 128; off > 0; off >>= 1) {
    if (t < off) { rs[t] += rs[t + off]; rq[t] += rq[t + off]; }
    __syncthreads();
  }
  if (t == 0) { part[(b * 64 + ch) * 2] = rs[0]; part[(b * 64 + ch) * 2 + 1] = rq[0]; }
}

__global__ void ln_final(const float* __restrict__ part, float* __restrict__ stats)
{
  const int b = blockIdx.x, t = threadIdx.x;  // 64 threads = 1 wave
  float s = part[(b * 64 + t) * 2];
  float q = part[(b * 64 + t) * 2 + 1];
  #pragma unroll
  for (int off = 32; off > 0; off >>= 1) { s += __shfl_down(s, off); q += __shfl_down(q, off); }
  if (t == 0) {
    const float invN = 1.0f / (float)(SS * DD);
    float mu = s * invN;
    float var = q * invN - mu * mu;
    stats[b * 2] = mu;
    stats[b * 2 + 1] = rsqrtf(var + 1e-8f);
  }
}

__global__ __launch_bounds__(256) void ln_apply_h(const float* __restrict__ src,
                                                  const float* __restrict__ g,
                                                  const float* __restrict__ bta,
                                                  const float* __restrict__ stats,
                                                  _Float16* __restrict__ dst)
{
  const long long n4 = (long long)BB * SS * DD / 4;
  const int SD4 = SS * DD / 4;
  for (long long i = (long long)blockIdx.x * 256 + threadIdx.x; i < n4;
       i += (long long)gridDim.x * 256) {
    const int b = (int)(i / SD4);
    const int sd4 = (int)(i - (long long)b * SD4);
    const float mu = stats[b * 2], rs = stats[b * 2 + 1];
    float4 v = ((const float4*)src)[i];
    float4 gg = ((const float4*)g)[sd4];
    float4 bb = ((const float4*)bta)[sd4];
    f16x4 r;
    r[0] = (_Float16)((v.x - mu) * rs * gg.x + bb.x);
    r[1] = (_Float16)((v.y - mu) * rs * gg.y + bb.y);
    r[2] = (_Float16)((v.z - mu) * rs * gg.z + bb.z);
    r[3] = (_Float16)((v.w - mu) * rs * gg.w + bb.w);
    ((f16x4*)dst)[i] = r;
  }
}

// gate[b,s] = dot(out_N[b,s,:], W_sgsa) + b_sgsa ; one wave per row
__global__ __launch_bounds__(256) void gate_k(const float* __restrict__ outN,
                                              const float* __restrict__ wsg,
                                              const float* __restrict__ bsg,
                                              float* __restrict__ gate)
{
  const int row = blockIdx.x * 4 + (threadIdx.x >> 6);
  const int l = threadIdx.x & 63;
  const float* src = outN + (size_t)row * DD;
  float s = 0.0f;
  #pragma unroll
  for (int i = 0; i < 12; i++) s += src[l + i * 64] * wsg[l + i * 64];
  #pragma unroll
  for (int off = 32; off > 0; off >>= 1) s += __shfl_down(s, off);
  if (l == 0) gate[row] = s + bsg[0];
}

// Pool stage A: grid (32 chunks, 16 batches); each block: 32 rows x 768 cols
__global__ __launch_bounds__(256) void pool_partial(const float* __restrict__ tokens,
                                                    const float* __restrict__ outN,
                                                    const float* __restrict__ gate,
                                                    float* __restrict__ part)
{
  const int b = blockIdx.y, ch = blockIdx.x, t = threadIdx.x;
  float st0 = 0, st1 = 0, st2 = 0, so0 = 0, so1 = 0, so2 = 0;
  float xt0 = -3.4e38f, xt1 = -3.4e38f, xt2 = -3.4e38f;
  float xo0 = -3.4e38f, xo1 = -3.4e38f, xo2 = -3.4e38f;
  const size_t rowbase = ((size_t)b * SS + ch * 32) * DD;
  for (int i = 0; i < 32; i++) {
    const float* tr = tokens + rowbase + (size_t)i * DD;
    const float* orw = outN + rowbase + (size_t)i * DD;
    const float g = gate[b * SS + ch * 32 + i];
    float t0 = tr[t], t1 = tr[t + 256], t2 = tr[t + 512];
    float o0 = orw[t] * g, o1 = orw[t + 256] * g, o2 = orw[t + 512] * g;
    st0 += t0; st1 += t1; st2 += t2;
    so0 += o0; so1 += o1; so2 += o2;
    xt0 = fmaxf(xt0, t0); xt1 = fmaxf(xt1, t1); xt2 = fmaxf(xt2, t2);
    xo0 = fmaxf(xo0, o0); xo1 = fmaxf(xo1, o1); xo2 = fmaxf(xo2, o2);
  }
  float* pb = part + (size_t)(b * 32 + ch) * 3072;
  pb[t] = st0;          pb[t + 256] = st1;          pb[t + 512] = st2;
  pb[768 + t] = so0;    pb[768 + t + 256] = so1;    pb[768 + t + 512] = so2;
  pb[1536 + t] = xt0;   pb[1536 + t + 256] = xt1;   pb[1536 + t + 512] = xt2;
  pb[2304 + t] = xo0;   pb[2304 + t + 256] = xo1;   pb[2304 + t + 512] = xo2;
}

// Pool stage B: combine 32 chunks -> pooled [B][4*768]
__global__ __launch_bounds__(256) void pool_final(const float* __restrict__ part,
                                                  float* __restrict__ pooled)
{
  const int idx = blockIdx.x * 256 + threadIdx.x;  // < B*D
  const int b = idx / DD, d = idx - b * DD;
  float st = 0, so = 0, xt = -3.4e38f, xo = -3.4e38f;
  for (int ch = 0; ch < 32; ch++) {
    const float* pb = part + (size_t)(b * 32 + ch) * 3072;
    st += pb[d]; so += pb[768 + d];
    xt = fmaxf(xt, pb[1536 + d]); xo = fmaxf(xo, pb[2304 + d]);
  }
  const float inv = 1.0f / (float)SS;
  pooled[(size_t)b * 3072 + d]        = st * inv;
  pooled[(size_t)b * 3072 + 768 + d]  = so * inv;
  pooled[(size_t)b * 3072 + 1536 + d] = xt;
  pooled[(size_t)b * 3072 + 2304 + d] = xo;
}

__global__ __launch_bounds__(256) void fc_k(const float* __restrict__ pooled,
                                            const float* __restrict__ Wf,
                                            const float* __restrict__ bf,
                                            float* __restrict__ outp)
{
  const int b = blockIdx.x, t = threadIdx.x;
  float p0 = 0.0f, p1 = 0.0f;
  #pragma unroll
  for (int i = 0; i < 12; i++) {
    const int j = t + i * 256;
    const float pv = pooled[(size_t)b * 3072 + j];
    p0 += pv * Wf[j * 2];
    p1 += pv * Wf[j * 2 + 1];
  }
  __shared__ float r0[256], r1[256];
  r0[t] = p0; r1[t] = p1; __syncthreads();
  #pragma unroll
  for (int off = 128; off > 0; off >>= 1) {
    if (t < off) { r0[t] += r0[t + off]; r1[t] += r1[t + off]; }
    __syncthreads();
  }
  if (t == 0) {
    outp[b * 2 + 0] = r0[0] + bf[0];
    outp[b * 2 + 1] = r1[0] + bf[1];
  }
}

// ---------------------------------------------------------------------------
// Host orchestration. fp16 GEMM I/O, fp32 softmax/LN/pool chain.
// Region map (byte offsets), peak ~202 MB:
//   R0 @ 0         (67.1MB f32): scores -> OUT -> attN_sc -> outN
//   R1 @ 67108864  (25.2MB f16): tokens_h -> out_ln_h -> attNT_h
//   R2 @ 92274688  (25.2MB f16): K_h -> KtN_h      (plane 0 of proj out)
//   R3 @ 117440512 (25.2MB f16): Q_h -> QtN_h      (plane 1)
//   R4 @ 142606336 (25.2MB f16): Vt_h -> VN_h      (plane 2)
//   R5 @ 167772160 (33.6MB f16): att_h -> attN_h
//   Wt @ 201326592 (3.5MB f16):  [3][768*768]
// ---------------------------------------------------------------------------
extern "C" void kernel_launch(void* const* d_in, const int* in_sizes, int n_in,
                              void* d_out, int out_size, void* d_ws, size_t ws_size,
                              hipStream_t stream)
{
  const float* tokens = (const float*)d_in[0];
  const float* Wk  = (const float*)d_in[1];
  const float* bk  = (const float*)d_in[2];
  const float* Wq  = (const float*)d_in[3];
  const float* bq  = (const float*)d_in[4];
  const float* Wv  = (const float*)d_in[5];
  const float* bv  = (const float*)d_in[6];
  const float* lng = (const float*)d_in[7];
  const float* lnb = (const float*)d_in[8];
  const float* Wsg = (const float*)d_in[9];
  const float* bsg = (const float*)d_in[10];
  const float* Wf  = (const float*)d_in[11];
  const float* bfn = (const float*)d_in[12];
  float* outp = (float*)d_out;
  (void)in_sizes; (void)n_in; (void)out_size; (void)ws_size;

  char* ws = (char*)d_ws;
  float*    R0   = (float*)(ws + 0);
  _Float16* R1   = (_Float16*)(ws + 67108864);
  _Float16* R2   = (_Float16*)(ws + 92274688);
  _Float16* R3   = (_Float16*)(ws + 117440512);
  _Float16* R4   = (_Float16*)(ws + 142606336);
  _Float16* R5   = (_Float16*)(ws + 167772160);
  _Float16* Wt   = (_Float16*)(ws + 201326592);   // 3,538,944 B
  float* bias3   = (float*)(ws + 204865536);      // 9,216 B
  float* part    = (float*)(ws + 204874752);      // 8,192 B
  float* stats   = (float*)(ws + 204882944);      // 128 B
  float* gate    = (float*)(ws + 204883072);      // 65,536 B
  float* ppart   = (float*)(ws + 204948608);      // 6,291,456 B
  float* pooled  = (float*)(ws + 211240064);      // 196,608 B (end ~201.7MB)

  const float fact = 0.036084391824351615f;  // 1/sqrt(768)
  const long long SD = (long long)SS * DD;   // 786432
  const long long S2 = (long long)SS * SS;   // 1048576
  const long long D2 = (long long)DD * DD;   // 589824
  const long long PL = (long long)BB * SD;   // 12582912 (one K/Q/V plane)

  // 1. casts / packing
  cast_f2h<<<2048, 256, 0, stream>>>(tokens, R1, PL / 4);
  transpose_f2h<<<dim3(24, 24), 256, 0, stream>>>(Wk, Wt,               768, 768);
  transpose_f2h<<<dim3(24, 24), 256, 0, stream>>>(Wq, Wt + 589824,      768, 768);
  transpose_f2h<<<dim3(24, 24), 256, 0, stream>>>(Wv, Wt + 2 * 589824,  768, 768);
  pack_bias<<<9, 256, 0, stream>>>(bk, bq, bv, bias3);

  // 2. Stage-1 projections, one launch: z0=K (R2), z1=Q (R3), z2=Vt (R4, transposed)
  gemm256<3, 1><<<dim3(9, 64, 1), 512, 0, stream>>>(R1, 0, Wt, 589824, bias3, 768,
                                                    (void*)R2, PL, BB * SS, DD, DD);
  // 3. scores = Q.K^T -> R0 fp32 [B,S,S]
  gemm256<0, 0><<<dim3(4, 4, 16), 512, 0, stream>>>(R3, SD, R2, SD, nullptr, 0,
                                                    (void*)R0, S2, SS, SS, DD);
  // 4. att_h = softmax(scores*fact) -> R5 fp16
  softmax_f2h<4><<<BB * SS, 256, 0, stream>>>(R0, R5, SS, fact);
  // 5. OUT = att @ V -> R0 fp32 [B,S,D]
  gemm256<0, 0><<<dim3(4, 3, 16), 512, 0, stream>>>(R5, S2, R4, SD, nullptr, 0,
                                                    (void*)R0, SD, SS, DD, SS);
  // 6. LayerNorm over (S,D) per batch: stats from fp32, out_ln_h -> R1 fp16
  ln_partial<<<dim3(64, 16), 256, 0, stream>>>(R0, part);
  ln_final<<<16, 64, 0, stream>>>(part, stats);
  ln_apply_h<<<2048, 256, 0, stream>>>(R0, lng, lnb, stats, R1);

  // 7. Stage-2 projections: z0=KtN (R2, tr), z1=QtN (R3, tr), z2=VN (R4, row-major)
  gemm256<4, 1><<<dim3(9, 64, 1), 512, 0, stream>>>(R1, 0, Wt, 589824, bias3, 768,
                                                    (void*)R2, PL, BB * SS, DD, DD);
  // 8. attN_sc[b,d,e] = QtN .NT. KtN -> R0 fp32 [B,D,D]
  gemm256<0, 0><<<dim3(3, 3, 16), 512, 0, stream>>>(R3, SD, R2, SD, nullptr, 0,
                                                    (void*)R0, D2, DD, DD, SS);
  // 9. attN_h = softmax -> R5 fp16
  softmax_f2h<3><<<BB * DD, 256, 0, stream>>>(R0, R5, DD, fact);
  // 10. attNT_h -> R1 (out_ln dead)
  transpose_b2h<<<dim3(24, 24, 16), 256, 0, stream>>>(R5, D2, R1, D2, DD, DD);
  // 11. outN = VN .NT. attNT -> R0 fp32 [B,S,D]
  gemm256<0, 0><<<dim3(4, 3, 16), 512, 0, stream>>>(R4, SD, R1, D2, nullptr, 0,
                                                    (void*)R0, SD, SS, DD, DD);

  // 12. gate, two-stage pooling, FC
  gate_k<<<4096, 256, 0, stream>>>(R0, Wsg, bsg, gate);
  pool_partial<<<dim3(32, BB), 256, 0, stream>>>(tokens, R0, gate, ppart);
  pool_final<<<48, 256, 0, stream>>>(ppart, pooled);
  fc_k<<<16, 256, 0, stream>>>(pooled, Wf, bfn, outp);
}

// Round 9
// 440.011 us; speedup vs baseline: 1.3675x; 1.0025x over previous
//
#include <hip/hip_runtime.h>

// Problem constants
#define BB 16
#define SS 1024
#define DD 768

typedef _Float16 f16x4 __attribute__((ext_vector_type(4)));
typedef _Float16 f16x8 __attribute__((ext_vector_type(8)));
typedef float f32x4 __attribute__((ext_vector_type(4)));

__device__ __forceinline__ void gload_lds16(const void* g, void* l) {
  __builtin_amdgcn_global_load_lds(
      (const __attribute__((address_space(1))) unsigned int*)g,
      (__attribute__((address_space(3))) unsigned int*)l, 16, 0, 0);
}

// ---------------------------------------------------------------------------
// 256x256 NT GEMM, 1-barrier/K-tile pipelined (T3+T4+T5). fp16 in, fp32 acc.
// C[z][m][n] = sum_k A[z][m][k] * Bt[z][n][k] (+ bias[z][n])
// 512 threads = 8 waves (2M x 4N), per-wave 128x64 out (8x4 frags), BK=64.
//
// LDS: 2 dbuf sides x {A,B} x 2 k-slabs x 16KB = 128 KiB.
// Slab layout: [128 pairs][8 slots x 16B]. Element (row R, k-chunk c) of the
// slab lives at pair P=R>>1, slot q = ((R&1)<<2) | (c ^ (P&3)).
//   Bank group = q alone: fragment-read octets hit all 8 bank groups ->
//   zero conflict (verified rounds 7/8: SQ_LDS_BANK_CONFLICT = 0).
//   Staging (inverse involution): thread t -> src row 2(t>>3)+((t&7)>>2),
//   chunk ((t&3))^((t>>3)&3); dest linear t*16 (+8192 for rows 128-255).
//   Wave covers 16 full 64B segments -> coalesced.
//
// Schedule per tile T (sd = T&1 read side, sn = sd^1 write side):
//   vmcnt(0)   // retires T's 8 loads, issued ONE FULL TILE ago (~3000 cyc)
//              // -> effectively free; only T's loads are outstanding here
//   barrier    // publishes both slabs of T; WAR-safe for writing sn (all
//              // tile-T-1 reads of sn were consumed by MFMAs before waves
//              // reached this barrier)
//   stage T+1 (both slabs, 8 loads) -> sn
//   issue ALL 24 ds_read_b128 into 6 independent frag sets
//   64-MFMA cluster (slab0 first: compiler's counted lgkmcnt starts slab0
//   MFMAs while slab1 reads drain -> LDS pipe (2304 cyc/CU/tile) overlaps
//   MFMA pipe (2482 cyc/CU/tile) instead of serializing [round-8 lesson]
//
// OUTM: 0 = fp32 row-major; 3 = f16, z<2 row-major / z==2 transposed;
//       4 = f16, z<2 transposed / z==2 row-major. Transposed = per-1024-row
//       batch: C[z][(b*N+c)*1024 + s], b=row>>10, s=row&1023.
// OUTM 3/4 (projections, A shared over z): grid (9, 64); XCD-aware decode
// puts all 9 blocks of one m-tile on ONE XCD (round-7 lesson).
// ---------------------------------------------------------------------------
template<int OUTM, int BIAS>
__global__ __launch_bounds__(512) void gemm256(
    const _Float16* __restrict__ A, long long aB,
    const _Float16* __restrict__ Bt, long long bB,
    const float* __restrict__ bias, int biasB,
    void* __restrict__ Cv, long long cB,
    int M, int N, int K)
{
  __shared__ __attribute__((aligned(16))) _Float16 lds[65536];  // 128 KiB
  const int t = threadIdx.x;
  int z, m0, n0;
  if (OUTM == 3 || OUTM == 4) {     // projection decode, XCD-grouped
    const int lin = blockIdx.x + 9 * blockIdx.y;   // 0..575
    const int xcd = lin & 7, idx = lin >> 3;       // idx 0..71
    const int mt  = xcd * 8 + idx / 9;
    const int zn  = idx % 9;
    z  = zn / 3;
    n0 = (zn % 3) * 256;
    m0 = mt * 256;
  } else {
    z = blockIdx.z;
    m0 = blockIdx.x * 256;
    n0 = blockIdx.y * 256;
  }
  const _Float16* Ab = A + (size_t)z * aB;
  const _Float16* Bb = Bt + (size_t)z * bB;

  const int l = t & 63, w = t >> 6;
  const int wr = (w >> 2) * 128, wc = (w & 3) * 64;
  const int lrow = l & 15, kq = l >> 4;
  // read-side swizzle (lane-constant)
  const int p2 = lrow >> 1;
  const int qread = ((lrow & 1) << 2) | (kq ^ (p2 & 3));
  const int fragoff = p2 * 128 + qread * 16;

  // staging lane constants (inverse of the same involution)
  const int sp = t >> 3, sq = t & 7;
  const int srow = 2 * sp + (sq >> 2);
  const int schk = (sq & 3) ^ (sp & 3);
  const size_t ldK = (size_t)K * 2;
  const char* pA0 = (const char*)Ab + (size_t)(m0 + srow) * ldK + schk * 16;
  const char* pA1 = pA0 + (size_t)128 * ldK;
  const char* pB0 = (const char*)Bb + (size_t)(n0 + srow) * ldK + schk * 16;
  const char* pB1 = pB0 + (size_t)128 * ldK;
  char* const ldsb = (char*)lds;
  const int dstt = t * 16;

  // stage one 16KB unit (mat: 0=A,1=B; k-slab s) of K-tile T into side sd
  auto stg = [&](int mat, int s, int T, int sd) {
    const char* g0 = (mat ? pB0 : pA0) + (size_t)T * 128 + s * 64;
    const char* g1 = (mat ? pB1 : pA1) + (size_t)T * 128 + s * 64;
    char* d = ldsb + sd * 65536 + mat * 32768 + s * 16384 + dstt;
    gload_lds16(g0, d);
    gload_lds16(g1, d + 8192);
  };

  f32x4 acc[8][4] = {};
  f16x8 b0[4], b1[4], a00[4], a01[4], a10[4], a11[4];  // 6 independent sets

  // prologue: tile 0 -> side 0
  stg(0, 0, 0, 0); stg(1, 0, 0, 0); stg(0, 1, 0, 0); stg(1, 1, 0, 0);

  const int NT = K >> 6;
  for (int T = 0; T < NT; ++T) {
    const int sd = T & 1, sn = sd ^ 1;
    const char* Abase = ldsb + sd * 65536;
    const char* Bbase = Abase + 32768;
    const bool pf = (T + 1) < NT;

    asm volatile("s_waitcnt vmcnt(0)" ::: "memory");
    __builtin_amdgcn_s_barrier();
    asm volatile("" ::: "memory");
    if (pf) {
      stg(0, 0, T + 1, sn); stg(1, 0, T + 1, sn);
      stg(0, 1, T + 1, sn); stg(1, 1, T + 1, sn);
    }

    // all 24 fragment reads (slab0 first so slab0 MFMAs can start early)
    #pragma unroll
    for (int n = 0; n < 4; n++)
      b0[n]  = *(const f16x8*)(Bbase + (wc + n * 16) * 64 + fragoff);
    #pragma unroll
    for (int mi = 0; mi < 4; mi++)
      a00[mi] = *(const f16x8*)(Abase + (wr + mi * 16) * 64 + fragoff);
    #pragma unroll
    for (int mi = 0; mi < 4; mi++)
      a01[mi] = *(const f16x8*)(Abase + (wr + 64 + mi * 16) * 64 + fragoff);
    #pragma unroll
    for (int n = 0; n < 4; n++)
      b1[n]  = *(const f16x8*)(Bbase + 16384 + (wc + n * 16) * 64 + fragoff);
    #pragma unroll
    for (int mi = 0; mi < 4; mi++)
      a10[mi] = *(const f16x8*)(Abase + 16384 + (wr + mi * 16) * 64 + fragoff);
    #pragma unroll
    for (int mi = 0; mi < 4; mi++)
      a11[mi] = *(const f16x8*)(Abase + 16384 + (wr + 64 + mi * 16) * 64 + fragoff);

    __builtin_amdgcn_s_setprio(1);
    #pragma unroll
    for (int mi = 0; mi < 4; mi++)
      #pragma unroll
      for (int n = 0; n < 4; n++)
        acc[mi][n] = __builtin_amdgcn_mfma_f32_16x16x32_f16(a00[mi], b0[n], acc[mi][n], 0, 0, 0);
    #pragma unroll
    for (int mi = 0; mi < 4; mi++)
      #pragma unroll
      for (int n = 0; n < 4; n++)
        acc[4 + mi][n] = __builtin_amdgcn_mfma_f32_16x16x32_f16(a01[mi], b0[n], acc[4 + mi][n], 0, 0, 0);
    #pragma unroll
    for (int mi = 0; mi < 4; mi++)
      #pragma unroll
      for (int n = 0; n < 4; n++)
        acc[mi][n] = __builtin_amdgcn_mfma_f32_16x16x32_f16(a10[mi], b1[n], acc[mi][n], 0, 0, 0);
    #pragma unroll
    for (int mi = 0; mi < 4; mi++)
      #pragma unroll
      for (int n = 0; n < 4; n++)
        acc[4 + mi][n] = __builtin_amdgcn_mfma_f32_16x16x32_f16(a11[mi], b1[n], acc[4 + mi][n], 0, 0, 0);
    __builtin_amdgcn_s_setprio(0);
  }

  // Epilogue. C/D layout: col = lane&15, row = 4*(lane>>4)+j.
  // acc[m] covers row wr + (m>>2)*64 + (m&3)*16.
  const int crow = (l >> 4) * 4, ccol = l & 15;
  #pragma unroll
  for (int m = 0; m < 8; ++m) {
    const int rq = m0 + wr + (m >> 2) * 64 + (m & 3) * 16 + crow;
    #pragma unroll
    for (int n = 0; n < 4; ++n) {
      const int c = n0 + wc + n * 16 + ccol;
      const float bv = BIAS ? bias[(size_t)z * biasB + c] : 0.0f;
      if (OUTM == 0) {
        float* C = (float*)Cv + (size_t)z * cB;
        #pragma unroll
        for (int j = 0; j < 4; j++)
          C[(size_t)(rq + j) * N + c] = acc[m][n][j] + bv;
      } else {
        _Float16* C = (_Float16*)Cv + (size_t)z * cB;
        const bool tr = (OUTM == 3) ? (z == 2) : (z < 2);
        if (tr) {
          const int bq = rq >> 10, s = rq & 1023;
          f16x4 o;
          #pragma unroll
          for (int j = 0; j < 4; j++) o[j] = (_Float16)(acc[m][n][j] + bv);
          *(f16x4*)&C[((size_t)(bq * N + c) << 10) + s] = o;
        } else {
          #pragma unroll
          for (int j = 0; j < 4; j++)
            C[(size_t)(rq + j) * N + c] = (_Float16)(acc[m][n][j] + bv);
        }
      }
    }
  }
}

// fp32 -> fp16 elementwise cast
__global__ __launch_bounds__(256) void cast_f2h(const float* __restrict__ in,
                                                _Float16* __restrict__ outp, long long n4)
{
  for (long long i = (long long)blockIdx.x * 256 + threadIdx.x; i < n4;
       i += (long long)gridDim.x * 256) {
    float4 v = ((const float4*)in)[i];
    f16x4 r;
    r[0] = (_Float16)v.x; r[1] = (_Float16)v.y; r[2] = (_Float16)v.z; r[3] = (_Float16)v.w;
    ((f16x4*)outp)[i] = r;
  }
}

// fp32 [R][C] -> fp16 [C][R] (weights transpose+cast)
__global__ __launch_bounds__(256) void transpose_f2h(const float* __restrict__ in,
                                                     _Float16* __restrict__ outp, int R, int C)
{
  __shared__ float tile[32][33];
  const int r0 = blockIdx.y * 32, c0 = blockIdx.x * 32;
  const int tx = threadIdx.x & 31, ty = threadIdx.x >> 5;  // 32 x 8
  #pragma unroll
  for (int i = 0; i < 4; i++)
    tile[ty + i * 8][tx] = in[(size_t)(r0 + ty + i * 8) * C + c0 + tx];
  __syncthreads();
  #pragma unroll
  for (int i = 0; i < 4; i++)
    outp[(size_t)(c0 + ty + i * 8) * R + r0 + tx] = (_Float16)tile[tx][ty + i * 8];
}

// fp16 [R][C] -> [C][R], batched over blockIdx.z
__global__ __launch_bounds__(256) void transpose_b2h(const _Float16* __restrict__ in, long long inB,
                                                     _Float16* __restrict__ outp, long long outB,
                                                     int R, int C)
{
  __shared__ _Float16 tile[32][33];
  const _Float16* ib = in + (size_t)blockIdx.z * inB;
  _Float16* ob = outp + (size_t)blockIdx.z * outB;
  const int r0 = blockIdx.y * 32, c0 = blockIdx.x * 32;
  const int tx = threadIdx.x & 31, ty = threadIdx.x >> 5;
  #pragma unroll
  for (int i = 0; i < 4; i++)
    tile[ty + i * 8][tx] = ib[(size_t)(r0 + ty + i * 8) * C + c0 + tx];
  __syncthreads();
  #pragma unroll
  for (int i = 0; i < 4; i++)
    ob[(size_t)(c0 + ty + i * 8) * R + r0 + tx] = tile[tx][ty + i * 8];
}

__global__ void pack_bias(const float* __restrict__ a, const float* __restrict__ b,
                          const float* __restrict__ c, float* __restrict__ o)
{
  int t = blockIdx.x * 256 + threadIdx.x;
  if (t < 768) o[t] = a[t];
  else if (t < 1536) o[t] = b[t - 768];
  else if (t < 2304) o[t] = c[t - 1536];
}

// Row softmax: fp32 in, fp16 out. L = VPT*256.
template<int VPT>
__global__ __launch_bounds__(256) void softmax_f2h(const float* __restrict__ X,
                                                   _Float16* __restrict__ Y,
                                                   int L, float scale)
{
  const size_t base = (size_t)blockIdx.x * L;
  const int t = threadIdx.x;
  float v[VPT];
  float m = -3.4e38f;
  #pragma unroll
  for (int j = 0; j < VPT; j++) { v[j] = X[base + t + j * 256]; m = fmaxf(m, v[j]); }
  __shared__ float red[256];
  red[t] = m; __syncthreads();
  #pragma unroll
  for (int off = 128; off > 0; off >>= 1) {
    if (t < off) red[t] = fmaxf(red[t], red[t + off]);
    __syncthreads();
  }
  m = red[0]; __syncthreads();
  float s = 0.0f;
  #pragma unroll
  for (int j = 0; j < VPT; j++) { v[j] = __expf((v[j] - m) * scale); s += v[j]; }
  red[t] = s; __syncthreads();
  #pragma unroll
  for (int off = 128; off > 0; off >>= 1) {
    if (t < off) red[t] += red[t + off];
    __syncthreads();
  }
  const float inv = 1.0f / red[0];
  #pragma unroll
  for (int j = 0; j < VPT; j++) Y[base + t + j * 256] = (_Float16)(v[j] * inv);
}

// LayerNorm over (S,D) jointly per batch
__global__ __launch_bounds__(256) void ln_partial(const float* __restrict__ src,
                                                  float* __restrict__ part)
{
  const int b = blockIdx.y, ch = blockIdx.x;   // 64 chunks per batch
  const float4* p = (const float4*)(src + (size_t)b * SS * DD) + (size_t)ch * 3072;
  const int t = threadIdx.x;
  float s = 0.0f, q = 0.0f;
  #pragma unroll
  for (int i = 0; i < 12; i++) {
    float4 v = p[t + i * 256];
    s += v.x + v.y + v.z + v.w;
    q += v.x * v.x + v.y * v.y + v.z * v.z + v.w * v.w;
  }
  __shared__ float rs[256], rq[256];
  rs[t] = s; rq[t] = q; __syncthreads();
  #pragma unroll
  for (int off = 128; off > 0; off >>= 1) {
    if (t < off) { rs[t] += rs[t + off]; rq[t] += rq[t + off]; }
    __syncthreads();
  }
  if (t == 0) { part[(b * 64 + ch) * 2] = rs[0]; part[(b * 64 + ch) * 2 + 1] = rq[0]; }
}

__global__ void ln_final(const float* __restrict__ part, float* __restrict__ stats)
{
  const int b = blockIdx.x, t = threadIdx.x;  // 64 threads = 1 wave
  float s = part[(b * 64 + t) * 2];
  float q = part[(b * 64 + t) * 2 + 1];
  #pragma unroll
  for (int off = 32; off > 0; off >>= 1) { s += __shfl_down(s, off); q += __shfl_down(q, off); }
  if (t == 0) {
    const float invN = 1.0f / (float)(SS * DD);
    float mu = s * invN;
    float var = q * invN - mu * mu;
    stats[b * 2] = mu;
    stats[b * 2 + 1] = rsqrtf(var + 1e-8f);
  }
}

__global__ __launch_bounds__(256) void ln_apply_h(const float* __restrict__ src,
                                                  const float* __restrict__ g,
                                                  const float* __restrict__ bta,
                                                  const float* __restrict__ stats,
                                                  _Float16* __restrict__ dst)
{
  const long long n4 = (long long)BB * SS * DD / 4;
  const int SD4 = SS * DD / 4;
  for (long long i = (long long)blockIdx.x * 256 + threadIdx.x; i < n4;
       i += (long long)gridDim.x * 256) {
    const int b = (int)(i / SD4);
    const int sd4 = (int)(i - (long long)b * SD4);
    const float mu = stats[b * 2], rs = stats[b * 2 + 1];
    float4 v = ((const float4*)src)[i];
    float4 gg = ((const float4*)g)[sd4];
    float4 bb = ((const float4*)bta)[sd4];
    f16x4 r;
    r[0] = (_Float16)((v.x - mu) * rs * gg.x + bb.x);
    r[1] = (_Float16)((v.y - mu) * rs * gg.y + bb.y);
    r[2] = (_Float16)((v.z - mu) * rs * gg.z + bb.z);
    r[3] = (_Float16)((v.w - mu) * rs * gg.w + bb.w);
    ((f16x4*)dst)[i] = r;
  }
}

// gate[b,s] = dot(out_N[b,s,:], W_sgsa) + b_sgsa ; one wave per row
__global__ __launch_bounds__(256) void gate_k(const float* __restrict__ outN,
                                              const float* __restrict__ wsg,
                                              const float* __restrict__ bsg,
                                              float* __restrict__ gate)
{
  const int row = blockIdx.x * 4 + (threadIdx.x >> 6);
  const int l = threadIdx.x & 63;
  const float* src = outN + (size_t)row * DD;
  float s = 0.0f;
  #pragma unroll
  for (int i = 0; i < 12; i++) s += src[l + i * 64] * wsg[l + i * 64];
  #pragma unroll
  for (int off = 32; off > 0; off >>= 1) s += __shfl_down(s, off);
  if (l == 0) gate[row] = s + bsg[0];
}

// Pool stage A: grid (32 chunks, 16 batches); each block: 32 rows x 768 cols
__global__ __launch_bounds__(256) void pool_partial(const float* __restrict__ tokens,
                                                    const float* __restrict__ outN,
                                                    const float* __restrict__ gate,
                                                    float* __restrict__ part)
{
  const int b = blockIdx.y, ch = blockIdx.x, t = threadIdx.x;
  float st0 = 0, st1 = 0, st2 = 0, so0 = 0, so1 = 0, so2 = 0;
  float xt0 = -3.4e38f, xt1 = -3.4e38f, xt2 = -3.4e38f;
  float xo0 = -3.4e38f, xo1 = -3.4e38f, xo2 = -3.4e38f;
  const size_t rowbase = ((size_t)b * SS + ch * 32) * DD;
  for (int i = 0; i < 32; i++) {
    const float* tr = tokens + rowbase + (size_t)i * DD;
    const float* orw = outN + rowbase + (size_t)i * DD;
    const float g = gate[b * SS + ch * 32 + i];
    float t0 = tr[t], t1 = tr[t + 256], t2 = tr[t + 512];
    float o0 = orw[t] * g, o1 = orw[t + 256] * g, o2 = orw[t + 512] * g;
    st0 += t0; st1 += t1; st2 += t2;
    so0 += o0; so1 += o1; so2 += o2;
    xt0 = fmaxf(xt0, t0); xt1 = fmaxf(xt1, t1); xt2 = fmaxf(xt2, t2);
    xo0 = fmaxf(xo0, o0); xo1 = fmaxf(xo1, o1); xo2 = fmaxf(xo2, o2);
  }
  float* pb = part + (size_t)(b * 32 + ch) * 3072;
  pb[t] = st0;          pb[t + 256] = st1;          pb[t + 512] = st2;
  pb[768 + t] = so0;    pb[768 + t + 256] = so1;    pb[768 + t + 512] = so2;
  pb[1536 + t] = xt0;   pb[1536 + t + 256] = xt1;   pb[1536 + t + 512] = xt2;
  pb[2304 + t] = xo0;   pb[2304 + t + 256] = xo1;   pb[2304 + t + 512] = xo2;
}

// Pool stage B: combine 32 chunks -> pooled [B][4*768]
__global__ __launch_bounds__(256) void pool_final(const float* __restrict__ part,
                                                  float* __restrict__ pooled)
{
  const int idx = blockIdx.x * 256 + threadIdx.x;  // < B*D
  const int b = idx / DD, d = idx - b * DD;
  float st = 0, so = 0, xt = -3.4e38f, xo = -3.4e38f;
  for (int ch = 0; ch < 32; ch++) {
    const float* pb = part + (size_t)(b * 32 + ch) * 3072;
    st += pb[d]; so += pb[768 + d];
    xt = fmaxf(xt, pb[1536 + d]); xo = fmaxf(xo, pb[2304 + d]);
  }
  const float inv = 1.0f / (float)SS;
  pooled[(size_t)b * 3072 + d]        = st * inv;
  pooled[(size_t)b * 3072 + 768 + d]  = so * inv;
  pooled[(size_t)b * 3072 + 1536 + d] = xt;
  pooled[(size_t)b * 3072 + 2304 + d] = xo;
}

__global__ __launch_bounds__(256) void fc_k(const float* __restrict__ pooled,
                                            const float* __restrict__ Wf,
                                            const float* __restrict__ bf,
                                            float* __restrict__ outp)
{
  const int b = blockIdx.x, t = threadIdx.x;
  float p0 = 0.0f, p1 = 0.0f;
  #pragma unroll
  for (int i = 0; i < 12; i++) {
    const int j = t + i * 256;
    const float pv = pooled[(size_t)b * 3072 + j];
    p0 += pv * Wf[j * 2];
    p1 += pv * Wf[j * 2 + 1];
  }
  __shared__ float r0[256], r1[256];
  r0[t] = p0; r1[t] = p1; __syncthreads();
  #pragma unroll
  for (int off = 128; off > 0; off >>= 1) {
    if (t < off) { r0[t] += r0[t + off]; r1[t] += r1[t + off]; }
    __syncthreads();
  }
  if (t == 0) {
    outp[b * 2 + 0] = r0[0] + bf[0];
    outp[b * 2 + 1] = r1[0] + bf[1];
  }
}

// ---------------------------------------------------------------------------
// Host orchestration. fp16 GEMM I/O, fp32 softmax/LN/pool chain.
// Region map (byte offsets), peak ~202 MB:
//   R0 @ 0         (67.1MB f32): scores -> OUT -> attN_sc -> outN
//   R1 @ 67108864  (25.2MB f16): tokens_h -> out_ln_h -> attNT_h
//   R2 @ 92274688  (25.2MB f16): K_h -> KtN_h      (plane 0 of proj out)
//   R3 @ 117440512 (25.2MB f16): Q_h -> QtN_h      (plane 1)
//   R4 @ 142606336 (25.2MB f16): Vt_h -> VN_h      (plane 2)
//   R5 @ 167772160 (33.6MB f16): att_h -> attN_h
//   Wt @ 201326592 (3.5MB f16):  [3][768*768]
// ---------------------------------------------------------------------------
extern "C" void kernel_launch(void* const* d_in, const int* in_sizes, int n_in,
                              void* d_out, int out_size, void* d_ws, size_t ws_size,
                              hipStream_t stream)
{
  const float* tokens = (const float*)d_in[0];
  const float* Wk  = (const float*)d_in[1];
  const float* bk  = (const float*)d_in[2];
  const float* Wq  = (const float*)d_in[3];
  const float* bq  = (const float*)d_in[4];
  const float* Wv  = (const float*)d_in[5];
  const float* bv  = (const float*)d_in[6];
  const float* lng = (const float*)d_in[7];
  const float* lnb = (const float*)d_in[8];
  const float* Wsg = (const float*)d_in[9];
  const float* bsg = (const float*)d_in[10];
  const float* Wf  = (const float*)d_in[11];
  const float* bfn = (const float*)d_in[12];
  float* outp = (float*)d_out;
  (void)in_sizes; (void)n_in; (void)out_size; (void)ws_size;

  char* ws = (char*)d_ws;
  float*    R0   = (float*)(ws + 0);
  _Float16* R1   = (_Float16*)(ws + 67108864);
  _Float16* R2   = (_Float16*)(ws + 92274688);
  _Float16* R3   = (_Float16*)(ws + 117440512);
  _Float16* R4   = (_Float16*)(ws + 142606336);
  _Float16* R5   = (_Float16*)(ws + 167772160);
  _Float16* Wt   = (_Float16*)(ws + 201326592);   // 3,538,944 B
  float* bias3   = (float*)(ws + 204865536);      // 9,216 B
  float* part    = (float*)(ws + 204874752);      // 8,192 B
  float* stats   = (float*)(ws + 204882944);      // 128 B
  float* gate    = (float*)(ws + 204883072);      // 65,536 B
  float* ppart   = (float*)(ws + 204948608);      // 6,291,456 B
  float* pooled  = (float*)(ws + 211240064);      // 196,608 B (end ~201.7MB)

  const float fact = 0.036084391824351615f;  // 1/sqrt(768)
  const long long SD = (long long)SS * DD;   // 786432
  const long long S2 = (long long)SS * SS;   // 1048576
  const long long D2 = (long long)DD * DD;   // 589824
  const long long PL = (long long)BB * SD;   // 12582912 (one K/Q/V plane)

  // 1. casts / packing
  cast_f2h<<<2048, 256, 0, stream>>>(tokens, R1, PL / 4);
  transpose_f2h<<<dim3(24, 24), 256, 0, stream>>>(Wk, Wt,               768, 768);
  transpose_f2h<<<dim3(24, 24), 256, 0, stream>>>(Wq, Wt + 589824,      768, 768);
  transpose_f2h<<<dim3(24, 24), 256, 0, stream>>>(Wv, Wt + 2 * 589824,  768, 768);
  pack_bias<<<9, 256, 0, stream>>>(bk, bq, bv, bias3);

  // 2. Stage-1 projections, one launch: z0=K (R2), z1=Q (R3), z2=Vt (R4, transposed)
  gemm256<3, 1><<<dim3(9, 64, 1), 512, 0, stream>>>(R1, 0, Wt, 589824, bias3, 768,
                                                    (void*)R2, PL, BB * SS, DD, DD);
  // 3. scores = Q.K^T -> R0 fp32 [B,S,S]
  gemm256<0, 0><<<dim3(4, 4, 16), 512, 0, stream>>>(R3, SD, R2, SD, nullptr, 0,
                                                    (void*)R0, S2, SS, SS, DD);
  // 4. att_h = softmax(scores*fact) -> R5 fp16
  softmax_f2h<4><<<BB * SS, 256, 0, stream>>>(R0, R5, SS, fact);
  // 5. OUT = att @ V -> R0 fp32 [B,S,D]
  gemm256<0, 0><<<dim3(4, 3, 16), 512, 0, stream>>>(R5, S2, R4, SD, nullptr, 0,
                                                    (void*)R0, SD, SS, DD, SS);
  // 6. LayerNorm over (S,D) per batch: stats from fp32, out_ln_h -> R1 fp16
  ln_partial<<<dim3(64, 16), 256, 0, stream>>>(R0, part);
  ln_final<<<16, 64, 0, stream>>>(part, stats);
  ln_apply_h<<<2048, 256, 0, stream>>>(R0, lng, lnb, stats, R1);

  // 7. Stage-2 projections: z0=KtN (R2, tr), z1=QtN (R3, tr), z2=VN (R4, row-major)
  gemm256<4, 1><<<dim3(9, 64, 1), 512, 0, stream>>>(R1, 0, Wt, 589824, bias3, 768,
                                                    (void*)R2, PL, BB * SS, DD, DD);
  // 8. attN_sc[b,d,e] = QtN .NT. KtN -> R0 fp32 [B,D,D]
  gemm256<0, 0><<<dim3(3, 3, 16), 512, 0, stream>>>(R3, SD, R2, SD, nullptr, 0,
                                                    (void*)R0, D2, DD, DD, SS);
  // 9. attN_h = softmax -> R5 fp16
  softmax_f2h<3><<<BB * DD, 256, 0, stream>>>(R0, R5, DD, fact);
  // 10. attNT_h -> R1 (out_ln dead)
  transpose_b2h<<<dim3(24, 24, 16), 256, 0, stream>>>(R5, D2, R1, D2, DD, DD);
  // 11. outN = VN .NT. attNT -> R0 fp32 [B,S,D]
  gemm256<0, 0><<<dim3(4, 3, 16), 512, 0, stream>>>(R4, SD, R1, D2, nullptr, 0,
                                                    (void*)R0, SD, SS, DD, DD);

  // 12. gate, two-stage pooling, FC
  gate_k<<<4096, 256, 0, stream>>>(R0, Wsg, bsg, gate);
  pool_partial<<<dim3(32, BB), 256, 0, stream>>>(tokens, R0, gate, ppart);
  pool_final<<<48, 256, 0, stream>>>(ppart, pooled);
  fc_k<<<16, 256, 0, stream>>>(pooled, Wf, bfn, outp);
}